// Round 6
// baseline (707.026 us; speedup 1.0000x reference)
//
#include <hip/hip_runtime.h>
#include <math.h>

using u16 = unsigned short;
using u32 = unsigned int;
using u64 = unsigned long long;
using bf16x8 = __attribute__((ext_vector_type(8))) short;
using f32x4  = __attribute__((ext_vector_type(4))) float;

#define C_DIM   512
#define HEADS   8
#define HDIM    64
#define P_DIM   64
#define A_TOK   256
#define VCAP    256
#define S_TOK   512
#define NWIN    64
#define NROW    32768      // NWIN * S_TOK
#define NPATCH  16384      // NWIN * A_TOK
#define MLP_DIM 2048
#define NV_TOT  2048

__device__ __forceinline__ float bf2f(u16 b) { return __uint_as_float(((u32)b) << 16); }
__device__ __forceinline__ u16 f2bf(float f) {
    u32 u = __float_as_uint(f);
    return (u16)((u + 0x7fffu + ((u >> 16) & 1u)) >> 16);   // RNE
}
__device__ __forceinline__ float4 bf4f(ushort4 v) {
    return make_float4(bf2f(v.x), bf2f(v.y), bf2f(v.z), bf2f(v.w));
}
// dtype-agnostic loads from RAW inputs: isbf=1 -> bf16, else f32
__device__ __forceinline__ float ldf(const void* p, size_t e, int isbf) {
    return isbf ? bf2f(((const u16*)p)[e]) : ((const float*)p)[e];
}
__device__ __forceinline__ float4 ld4(const void* p, size_t e, int isbf) {  // e % 4 == 0
    if (isbf) return bf4f(*(const ushort4*)((const u16*)p + e));
    return *(const float4*)((const float*)p + e);
}
// async global->LDS, 16B per lane; lds dest must be wave-uniform-base + lane*16
__device__ __forceinline__ void gload16(const u16* g, u16* l) {
    __builtin_amdgcn_global_load_lds(
        (const __attribute__((address_space(1))) u32*)g,
        (__attribute__((address_space(3))) u32*)l, 16, 0, 0);
}
// tanh-form GELU via sigmoid: x*sigmoid(1.5957691x + 0.0713548x^3); |err| <= ~3e-4
__device__ __forceinline__ float fast_gelu(float x) {
    float x2 = x * x;
    float z = x * (-1.5957691216f - 0.07135481283f * x2);
    return x / (1.f + __expf(z));
}

// ---------------- dtype detector: vote on low-16-bits-as-bf16 plausibility ----------------
__global__ void detect_kernel(const u32* __restrict__ patch, int* __restrict__ flag)
{
    __shared__ int sm[256];
    int t = threadIdx.x;
    int cnt = 0;
    for (int i = t; i < 4096; i += 256) {
        u32 w = patch[i];
        float v = __uint_as_float((w & 0xffffu) << 16);
        float a = fabsf(v);
        if (a > 1e-8f && a < 1e4f) cnt++;
    }
    sm[t] = cnt;
    __syncthreads();
    for (int o = 128; o; o >>= 1) { if (t < o) sm[t] += sm[t + o]; __syncthreads(); }
    if (t == 0) *flag = (sm[0] > 2458) ? 1 : 0;    // >60% plausible => bf16 world
}

// ------------- merged weight transposes: all six [K][N] -> [N][K] bf16 in one dispatch -------------
__global__ void wtrans_all_kernel(const void* __restrict__ wq, const void* __restrict__ wk,
                                  const void* __restrict__ wv, const void* __restrict__ wo,
                                  const void* __restrict__ w1, const void* __restrict__ w2,
                                  u16* __restrict__ wqkvT, u16* __restrict__ woT,
                                  u16* __restrict__ w1T, u16* __restrict__ w2T,
                                  const int* __restrict__ flagp)
{
    __shared__ u16 tile[32][33];
    int isbf = *flagp;
    int id = blockIdx.x;
    const void* in; u16* out; int K, N; float sc = 1.f;
    if (id < 256)       { in = wq; out = wqkvT;              K = 512;  N = 512;  sc = 0.125f; }
    else if (id < 512)  { id -= 256;  in = wk; out = wqkvT + 512 * 512;  K = 512;  N = 512; }
    else if (id < 768)  { id -= 512;  in = wv; out = wqkvT + 1024 * 512; K = 512;  N = 512; }
    else if (id < 1024) { id -= 768;  in = wo; out = woT;    K = 512;  N = 512; }
    else if (id < 2048) { id -= 1024; in = w1; out = w1T;    K = 512;  N = 2048; }
    else                { id -= 2048; in = w2; out = w2T;    K = 2048; N = 512; }
    int ntx = N >> 5;
    int n0 = (id % ntx) * 32, k0 = (id / ntx) * 32;
    int tx = threadIdx.x, ty = threadIdx.y;   // block (32, 8)
    #pragma unroll
    for (int i = 0; i < 4; i++)
        tile[ty + i * 8][tx] = f2bf(sc * ldf(in, (size_t)(k0 + ty + i * 8) * N + (n0 + tx), isbf));
    __syncthreads();
    #pragma unroll
    for (int i = 0; i < 4; i++)
        out[(size_t)(n0 + ty + i * 8) * K + (k0 + tx)] = tile[tx][ty + i * 8];
}

// ---------------- fused q/k/v bias vector (q part pre-scaled), f32 ----------------
__global__ void prep_bias_kernel(const void* __restrict__ bq, const void* __restrict__ bk,
                                 const void* __restrict__ bv,
                                 const int* __restrict__ flagp, float* __restrict__ bqkv)
{
    int isbf = *flagp;
    int t = blockIdx.x * 256 + threadIdx.x;
    if (t < 512)       bqkv[t] = 0.125f * ldf(bq, t, isbf);
    else if (t < 1024) bqkv[t] = ldf(bk, t - 512, isbf);
    else if (t < 1536) bqkv[t] = ldf(bv, t - 1024, isbf);
}

// ---------------- per-window voxel selection (stable order, cap 256) ----------------
__global__ void voxsel_kernel(const int* __restrict__ vy, const int* __restrict__ vx,
                              int* __restrict__ sel)
{
    int n = blockIdx.x;                 // 64 windows, 64 threads (1 wave)
    int lane = threadIdx.x;
    int y0 = (n >> 3) << 3, x0 = (n & 7) << 3;
    int count = 0;
    for (int base = 0; base < NV_TOT; base += 64) {
        int v = base + lane;
        int yy = vy[v], xx = vx[v];
        bool m = (yy >= y0) && (yy < y0 + 16) && (xx >= x0) && (xx < x0 + 16);
        u64 mask = __ballot(m);
        int pos = count + __popcll(mask & ((1ull << lane) - 1ull));
        if (m && pos < VCAP) sel[n * VCAP + pos] = v;
        count += __popcll(mask);
    }
    for (int j = lane; j < VCAP; j += 64)
        if (j >= count) sel[n * VCAP + j] = -1;
}

// ---------------- gather tokens + LN1 -> h (bf16), validity flags ----------------
__global__ __launch_bounds__(256) void ln1_kernel(
    const void* __restrict__ patch, const void* __restrict__ vox,
    const void* __restrict__ g, const void* __restrict__ b,
    const int* __restrict__ sel, const int* __restrict__ flagp,
    u16* __restrict__ h, unsigned char* __restrict__ validk)
{
    int isbf = *flagp;
    int r = blockIdx.x * 4 + (threadIdx.x >> 6);    // one wave per row
    int lane = threadIdx.x & 63;
    int n = r >> 9, s = r & 511;
    const void* tok = nullptr;
    size_t base = 0;
    bool valid;
    if (s < A_TOK) {
        int wy = s >> 4, wx = s & 15;
        int iy = ((n >> 3) << 3) + wy, ix = ((n & 7) << 3) + wx;
        valid = (iy < P_DIM) && (ix < P_DIM);
        tok = patch; base = (size_t)(iy * P_DIM + ix) * C_DIM;
    } else {
        int idx = sel[n * VCAP + (s - A_TOK)];
        valid = (idx >= 0);
        tok = vox; base = valid ? (size_t)idx * C_DIM : 0;
    }
    float4 xa = make_float4(0.f, 0.f, 0.f, 0.f), xb = xa;
    if (valid) {
        xa = ld4(tok, base + lane * 4, isbf);
        xb = ld4(tok, base + 256 + lane * 4, isbf);
    }
    float sum = xa.x + xa.y + xa.z + xa.w + xb.x + xb.y + xb.z + xb.w;
    float sq  = xa.x * xa.x + xa.y * xa.y + xa.z * xa.z + xa.w * xa.w
              + xb.x * xb.x + xb.y * xb.y + xb.z * xb.z + xb.w * xb.w;
    #pragma unroll
    for (int off = 32; off; off >>= 1) {
        sum += __shfl_xor(sum, off, 64);
        sq  += __shfl_xor(sq,  off, 64);
    }
    float mean = sum * (1.f / C_DIM);
    float var  = fmaxf(sq * (1.f / C_DIM) - mean * mean, 0.f);
    float rstd = rsqrtf(var + 1e-5f);
    float4 ga = ld4(g, lane * 4, isbf);
    float4 gb = ld4(g, 256 + lane * 4, isbf);
    float4 ba = ld4(b, lane * 4, isbf);
    float4 bb = ld4(b, 256 + lane * 4, isbf);
    ushort4 oa, ob;
    oa.x = f2bf((xa.x - mean) * rstd * ga.x + ba.x);
    oa.y = f2bf((xa.y - mean) * rstd * ga.y + ba.y);
    oa.z = f2bf((xa.z - mean) * rstd * ga.z + ba.z);
    oa.w = f2bf((xa.w - mean) * rstd * ga.w + ba.w);
    ob.x = f2bf((xb.x - mean) * rstd * gb.x + bb.x);
    ob.y = f2bf((xb.y - mean) * rstd * gb.y + bb.y);
    ob.z = f2bf((xb.z - mean) * rstd * gb.z + bb.z);
    ob.w = f2bf((xb.w - mean) * rstd * gb.w + bb.w);
    ((ushort4*)(h + (size_t)r * C_DIM))[lane]      = oa;
    ((ushort4*)(h + (size_t)r * C_DIM))[lane + 64] = ob;
    if (lane == 0) validk[r] = valid ? 1 : 0;
}

// ---------------- LN2 over bf16 rows -> bf16 ----------------
__global__ __launch_bounds__(256) void ln2_kernel(
    const u16* __restrict__ x,
    const void* __restrict__ g, const void* __restrict__ b,
    const int* __restrict__ flagp,
    u16* __restrict__ h2)
{
    int isbf = *flagp;
    int r = blockIdx.x * 4 + (threadIdx.x >> 6);
    int lane = threadIdx.x & 63;
    const u16* src = x + (size_t)r * C_DIM;
    float4 xa = bf4f(((const ushort4*)src)[lane]);
    float4 xb = bf4f(((const ushort4*)src)[lane + 64]);
    float sum = xa.x + xa.y + xa.z + xa.w + xb.x + xb.y + xb.z + xb.w;
    float sq  = xa.x * xa.x + xa.y * xa.y + xa.z * xa.z + xa.w * xa.w
              + xb.x * xb.x + xb.y * xb.y + xb.z * xb.z + xb.w * xb.w;
    #pragma unroll
    for (int off = 32; off; off >>= 1) {
        sum += __shfl_xor(sum, off, 64);
        sq  += __shfl_xor(sq,  off, 64);
    }
    float mean = sum * (1.f / C_DIM);
    float var  = fmaxf(sq * (1.f / C_DIM) - mean * mean, 0.f);
    float rstd = rsqrtf(var + 1e-5f);
    float4 ga = ld4(g, lane * 4, isbf);
    float4 gb = ld4(g, 256 + lane * 4, isbf);
    float4 ba = ld4(b, lane * 4, isbf);
    float4 bb = ld4(b, 256 + lane * 4, isbf);
    ushort4 oa, ob;
    oa.x = f2bf((xa.x - mean) * rstd * ga.x + ba.x);
    oa.y = f2bf((xa.y - mean) * rstd * ga.y + ba.y);
    oa.z = f2bf((xa.z - mean) * rstd * ga.z + ba.z);
    oa.w = f2bf((xa.w - mean) * rstd * ga.w + ba.w);
    ob.x = f2bf((xb.x - mean) * rstd * gb.x + bb.x);
    ob.y = f2bf((xb.y - mean) * rstd * gb.y + bb.y);
    ob.z = f2bf((xb.z - mean) * rstd * gb.z + bb.z);
    ob.w = f2bf((xb.w - mean) * rstd * gb.w + bb.w);
    ((ushort4*)(h2 + (size_t)r * C_DIM))[lane]      = oa;
    ((ushort4*)(h2 + (size_t)r * C_DIM))[lane + 64] = ob;
}

// ---------------- generic bf16 MFMA GEMM: C = op(A @ B^T + bias) ----------------
// Grid-strided n-tile loop: each block handles (N/128)/gridDim.x tiles {x, x+gx, ...}
// -> same-XCD A-tile reuse (cuts cross-XCD L2 refetch) + amortized prologue.
#define GF_GELU      2
#define GF_RES_BF16  8    // += res (bf16, [M][N])
#define GF_RES_PATCH 16   // += gathered patch token (raw dtype), valid positions only
#define GF_QKV       32   // N=1536: cols 0-511 q (compact, patch rows), 512-1023 k, 1024-1535 v^T

__global__ __launch_bounds__(256) void gemm_kernel(
    const u16* __restrict__ A, const u16* __restrict__ BT,
    const void* __restrict__ bias,
    void* __restrict__ Cout, void* __restrict__ Cout2, void* __restrict__ Cout3,
    const void* __restrict__ resv,
    const int* __restrict__ flagp,
    int M, int N, int K, int flags, int ldc)
{
    __shared__ u16 smem[2 * 128 * 64];   // As = smem, Bs = smem+8192 (u16); epilogue stage reuse
    int tid = threadIdx.x;
    int m0 = blockIdx.y * 128;
    int isbf = *flagp;
    int w = tid >> 6, lane = tid & 63;
    int wr = (w >> 1) * 64, wc = (w & 1) * 64;
    int l16 = lane & 15, quad = lane >> 4;
    u16* As = smem;
    u16* Bs = smem + 8192;
    int swz = (l16 & 7);                   // frag-read chunk swizzle key
    int ntiles = (N >> 7) / gridDim.x;

    for (int t = 0; t < ntiles; t++) {
        int nt = blockIdx.x + t * gridDim.x;
        int n0 = nt << 7;
        int region = (flags & GF_QKV) ? (nt >> 2) : 0;   // 0:q 1:k 2:v^T
        if ((flags & GF_QKV) && region == 0 && (m0 & 511) >= 256) continue;  // no Q for voxel rows
        bool vtb = (flags & GF_QKV) && (region == 2);    // transposed-output block
        if (t > 0) __syncthreads();        // prior tile's epilogue LDS reads done before re-stage

        f32x4 acc[4][4];
        #pragma unroll
        for (int i = 0; i < 4; i++)
            #pragma unroll
            for (int j = 0; j < 4; j++) { acc[i][j][0] = 0.f; acc[i][j][1] = 0.f; acc[i][j][2] = 0.f; acc[i][j][3] = 0.f; }

        const u16* Xs = vtb ? Bs : As;     // first operand rows -> D rows
        const u16* Ys = vtb ? As : Bs;
        for (int k0 = 0; k0 < K; k0 += 64) {
            #pragma unroll
            for (int it = 0; it < 4; it++) {
                int c = (it * 4 + w) * 64 + lane;   // 0..1023 chunk slots
                int row = c >> 3, phys = c & 7;
                int kc = phys ^ (row & 7);          // XOR swizzle: break 128B-stride bank aliasing
                gload16(A  + (size_t)(m0 + row) * K + k0 + kc * 8, As + (size_t)c * 8);
                gload16(BT + (size_t)(n0 + row) * K + k0 + kc * 8, Bs + (size_t)c * 8);
            }
            __syncthreads();
            #pragma unroll
            for (int ks = 0; ks < 2; ks++) {
                bf16x8 a[4], b[4];
                #pragma unroll
                for (int i = 0; i < 4; i++) {
                    int chunk = (ks * 4 + quad) ^ swz;
                    a[i] = *(const bf16x8*)&Xs[(wr + i * 16 + l16) * 64 + chunk * 8];
                }
                #pragma unroll
                for (int j = 0; j < 4; j++) {
                    int chunk = (ks * 4 + quad) ^ swz;
                    b[j] = *(const bf16x8*)&Ys[(wc + j * 16 + l16) * 64 + chunk * 8];
                }
                #pragma unroll
                for (int i = 0; i < 4; i++)
                    #pragma unroll
                    for (int j = 0; j < 4; j++)
                        acc[i][j] = __builtin_amdgcn_mfma_f32_16x16x32_bf16(a[i], b[j], acc[i][j], 0, 0, 0);
            }
            __syncthreads();
        }

        // ---------- epilogue (always bf16, LDS-staged, coalesced 128B rows) ----------
        u16* st = smem + w * 4096;          // per-wave 64x64 bf16 stage (8KB, reuses tile LDS)
        #pragma unroll
        for (int i = 0; i < 4; i++) {
            #pragma unroll
            for (int j = 0; j < 4; j++) {
                int gcol = n0 + wc + j * 16 + l16;
                float bc = 0.f;
                if (flags & GF_QKV) { if (!vtb) bc = ((const float*)bias)[gcol]; }
                else if (bias) bc = ldf(bias, gcol, isbf);
                #pragma unroll
                for (int r2 = 0; r2 < 4; r2++) {
                    int lrow = wr + i * 16 + quad * 4 + r2;
                    int grow = m0 + lrow;
                    if (vtb) bc = ((const float*)bias)[n0 + lrow];   // channel-indexed bias
                    float v = acc[i][j][r2] + bc;
                    if (flags & GF_GELU) v = fast_gelu(v);
                    if (flags & GF_RES_BF16) v += bf2f(((const u16*)resv)[(size_t)grow * N + gcol]);
                    if (flags & GF_RES_PATCH) {
                        int nn = grow >> 8, s = grow & 255;
                        int iy = ((nn >> 3) << 3) + (s >> 4);
                        int ix = ((nn & 7) << 3) + (s & 15);
                        if (iy < P_DIM && ix < P_DIM)
                            v += ldf(resv, (size_t)(iy * P_DIM + ix) * C_DIM + gcol, isbf);
                    }
                    st[(i * 16 + quad * 4 + r2) * 64 + j * 16 + l16] = f2bf(v);
                }
            }
        }
        asm volatile("" ::: "memory");   // same-wave LDS: block reorder, no barrier needed
        u16* cdst; int cst;
        if (flags & GF_QKV) {
            if (region == 0) {          // q: compact patch rows, pre-scaled
                cst = 512;
                cdst = (u16*)Cout  + (size_t)(((m0 >> 9) << 8) + (m0 & 255) + wr) * 512 + (n0 + wc);
            } else if (region == 1) {   // k
                cst = 512;
                cdst = (u16*)Cout2 + (size_t)(m0 + wr) * 512 + (n0 - 512 + wc);
            } else {                    // v^T: rows = channels, cols = tokens
                cst = NROW;
                cdst = (u16*)Cout3 + (size_t)(n0 - 1024 + wr) * NROW + (m0 + wc);
            }
        } else {
            cst = ldc;
            cdst = (u16*)Cout + (size_t)(m0 + wr) * ldc + (n0 + wc);
        }
        #pragma unroll
        for (int rr = 0; rr < 8; rr++) {
            int row = rr * 8 + (lane >> 3);
            uint4 val = *(const uint4*)&st[row * 64 + (lane & 7) * 8];
            *(uint4*)(cdst + (size_t)row * cst + (lane & 7) * 8) = val;   // 128B/row coalesced
        }
    }
}

// ---------------- flash attention per (window, head); patch queries only ----------------
__global__ __launch_bounds__(256) void attn_kernel(
    const u16* __restrict__ q, const u16* __restrict__ k, const u16* __restrict__ vtg,
    const unsigned char* __restrict__ validk,
    u16* __restrict__ o)
{
    __shared__ u16 sK[64 * 64];          // [key][d], DMA-staged, swizzled chunks
    __shared__ u16 sV[64 * 64];          // [d][key], DMA-staged from V^T, swizzled chunks
    __shared__ u16 sP[4 * 64 * 64];      // per-wave P tile, chunk-swizzled (48KB total LDS)
    int h = blockIdx.x, n = blockIdx.y;
    int tid = threadIdx.x;
    int w = tid >> 6, lane = tid & 63;
    int l16 = lane & 15, quad = lane >> 4;
    int swz = (l16 & 7);

    bf16x8 qf[4][2];
    #pragma unroll
    for (int i = 0; i < 4; i++)
        #pragma unroll
        for (int ks = 0; ks < 2; ks++) {
            int row = n * A_TOK + w * 64 + i * 16 + l16;       // compact q
            int col = h * HDIM + ks * 32 + quad * 8;
            qf[i][ks] = *(const bf16x8*)(q + (size_t)row * C_DIM + col);
        }

    f32x4 oacc[4][4];
    float lsum[4][4];
    #pragma unroll
    for (int i = 0; i < 4; i++)
        #pragma unroll
        for (int j = 0; j < 4; j++) {
            oacc[i][j][0] = 0.f; oacc[i][j][1] = 0.f; oacc[i][j][2] = 0.f; oacc[i][j][3] = 0.f;
            lsum[i][j] = 0.f;
        }

    for (int ktile = 0; ktile < 8; ktile++) {
        __syncthreads();                       // prior tile's readers done before overwrite
        #pragma unroll
        for (int it = 0; it < 2; it++) {
            int c = it * 256 + w * 64 + lane;  // 0..511 chunk slots
            int row = c >> 3, phys = c & 7;
            int kc = phys ^ (row & 7);
            int grow = n * S_TOK + ktile * 64 + row;
            gload16(k + (size_t)grow * C_DIM + h * HDIM + kc * 8, sK + (size_t)c * 8);
            gload16(vtg + (size_t)(h * HDIM + row) * (size_t)NROW + n * S_TOK + ktile * 64 + kc * 8,
                    sV + (size_t)c * 8);
        }
        __syncthreads();

        f32x4 sacc[4][4];
        #pragma unroll
        for (int i = 0; i < 4; i++)
            #pragma unroll
            for (int j = 0; j < 4; j++) { sacc[i][j][0] = 0.f; sacc[i][j][1] = 0.f; sacc[i][j][2] = 0.f; sacc[i][j][3] = 0.f; }
        #pragma unroll
        for (int ks = 0; ks < 2; ks++) {
            int chunk = (ks * 4 + quad) ^ swz;
            bf16x8 bfr[4];
            #pragma unroll
            for (int j = 0; j < 4; j++) bfr[j] = *(const bf16x8*)&sK[(j * 16 + l16) * 64 + chunk * 8];
            #pragma unroll
            for (int i = 0; i < 4; i++)
                #pragma unroll
                for (int j = 0; j < 4; j++)
                    sacc[i][j] = __builtin_amdgcn_mfma_f32_16x16x32_bf16(qf[i][ks], bfr[j], sacc[i][j], 0, 0, 0);
        }

        bool kvalid[4];
        #pragma unroll
        for (int j = 0; j < 4; j++)
            kvalid[j] = validk[n * S_TOK + ktile * 64 + j * 16 + l16] != 0;

        #pragma unroll
        for (int i = 0; i < 4; i++)
            #pragma unroll
            for (int r2 = 0; r2 < 4; r2++) {
                int prow = i * 16 + quad * 4 + r2;
                #pragma unroll
                for (int j = 0; j < 4; j++) {
                    float p = kvalid[j] ? __expf(sacc[i][j][r2]) : 0.f;
                    lsum[i][r2] += p;
                    int col = j * 16 + l16;
                    int chunk = (col >> 3) ^ (prow & 7);
                    sP[(w * 64 + prow) * 64 + chunk * 8 + (col & 7)] = f2bf(p);
                }
            }
        asm volatile("" ::: "memory");   // per-wave LDS: forbid read-before-write reorder
        #pragma unroll
        for (int ks = 0; ks < 2; ks++) {
            int chunk = (ks * 4 + quad) ^ swz;
            bf16x8 pa[4], vb[4];
            #pragma unroll
            for (int i = 0; i < 4; i++)   pa[i]  = *(const bf16x8*)&sP[(w * 64 + i * 16 + l16) * 64 + chunk * 8];
            #pragma unroll
            for (int jd = 0; jd < 4; jd++) vb[jd] = *(const bf16x8*)&sV[(jd * 16 + l16) * 64 + chunk * 8];
            #pragma unroll
            for (int i = 0; i < 4; i++)
                #pragma unroll
                for (int jd = 0; jd < 4; jd++)
                    oacc[i][jd] = __builtin_amdgcn_mfma_f32_16x16x32_bf16(pa[i], vb[jd], oacc[i][jd], 0, 0, 0);
        }
    }

    // normalize, stage O per-wave in LDS, coalesced 128B stores
    asm volatile("" ::: "memory");
    u16* ost = sP + w * 4096;            // flat 64x64 region, stride 64 (sP data dead)
    #pragma unroll
    for (int i = 0; i < 4; i++) {
        #pragma unroll
        for (int r2 = 0; r2 < 4; r2++) {
            float l = lsum[i][r2];
            #pragma unroll
            for (int off = 8; off; off >>= 1)
                l += __shfl_xor(l, off, 64);
            float inv = (l > 0.f) ? 1.f / l : 0.f;
            #pragma unroll
            for (int jd = 0; jd < 4; jd++)
                ost[(i * 16 + quad * 4 + r2) * 64 + jd * 16 + l16] = f2bf(oacc[i][jd][r2] * inv);
        }
    }
    asm volatile("" ::: "memory");
    u16* obase = o + (size_t)(n * A_TOK + w * 64) * C_DIM + h * HDIM;
    #pragma unroll
    for (int rr = 0; rr < 8; rr++) {
        int row = rr * 8 + (lane >> 3);
        uint4 val = *(const uint4*)&ost[row * 64 + (lane & 7) * 8];
        *(uint4*)(obase + (size_t)row * C_DIM + (lane & 7) * 8) = val;
    }
}

// ---------------- final gather-average (bf16 input) ----------------
__global__ __launch_bounds__(256) void gather_kernel(const u16* __restrict__ xf,
                                                     void* __restrict__ out,
                                                     const int* __restrict__ flagp)
{
    int isbf = *flagp;
    int gid = blockIdx.x * 256 + threadIdx.x;    // pixel*128 + 4-elem chunk
    int p = gid >> 7, cv = gid & 127;
    int py = p >> 6, px = p & 63;
    float4 acc = make_float4(0.f, 0.f, 0.f, 0.f);
    int cnt = 0;
    #pragma unroll
    for (int dy = 0; dy < 2; dy++) {
        int y0 = ((py >> 3) - dy) << 3;
        if (y0 < 0) continue;
        #pragma unroll
        for (int dx = 0; dx < 2; dx++) {
            int x0 = ((px >> 3) - dx) << 3;
            if (x0 < 0) continue;
            int n = ((y0 >> 3) << 3) + (x0 >> 3);
            int s = (py - y0) * 16 + (px - x0);
            float4 t = bf4f(((const ushort4*)(xf + (size_t)(n * A_TOK + s) * C_DIM))[cv]);
            acc.x += t.x; acc.y += t.y; acc.z += t.z; acc.w += t.w;
            cnt++;
        }
    }
    float inv = 1.f / (float)cnt;
    acc.x *= inv; acc.y *= inv; acc.z *= inv; acc.w *= inv;
    if (isbf) {
        ushort4 o;
        o.x = f2bf(acc.x); o.y = f2bf(acc.y); o.z = f2bf(acc.z); o.w = f2bf(acc.w);
        ((ushort4*)out)[gid] = o;
    } else {
        ((float4*)out)[gid] = acc;
    }
}

extern "C" void kernel_launch(void* const* d_in, const int* in_sizes, int n_in,
                              void* d_out, int out_size, void* d_ws, size_t ws_size,
                              hipStream_t stream)
{
    const void* patch = d_in[0];
    const void* vox   = d_in[1];
    const void* ln1g  = d_in[2];
    const void* ln1b  = d_in[3];
    const void* wq = d_in[4];  const void* bq = d_in[5];
    const void* wk = d_in[6];  const void* bk = d_in[7];
    const void* wv = d_in[8];  const void* bv = d_in[9];
    const void* wo = d_in[10]; const void* bo = d_in[11];
    const void* ln2g = d_in[12];
    const void* ln2b = d_in[13];
    const void* w1 = d_in[14]; const void* b1 = d_in[15];
    const void* w2 = d_in[16]; const void* b2 = d_in[17];
    const int* vpy = (const int*)d_in[18];
    const int* vpx = (const int*)d_in[19];

    const size_t MB = 1ull << 20;
    char* ws = (char*)d_ws;
    if (ws_size < 183 * MB) return;   // insufficient workspace -> visible failure

    u16*  hbuf  = (u16*)(ws + 0);          // [32768][512] bf16, 32MB
    u16*  kbuf  = (u16*)(ws + 32 * MB);    // [32768][512] bf16, 32MB
    u16*  vtt   = (u16*)(ws + 64 * MB);    // V^T [512][32768] bf16, 32MB
    u16*  qbuf  = (u16*)(ws + 96 * MB);    // [16384][512] bf16, 16MB (compact patch)
    u16*  obuf  = (u16*)(ws + 112 * MB);   // 16MB
    u16*  xbuf16 = (u16*)(ws + 128 * MB);  // x residual [16384][512] bf16, 16MB
    u16*  h2buf = (u16*)(ws + 160 * MB);   // 16MB
    u16*  tbuf  = (u16*)(ws + 0);          // [16384][2048] bf16, 64MB (reuse h+k, dead)
    u16*  xfbuf = (u16*)(ws + 64 * MB);    // [16384][512] bf16, 16MB (reuse vtt, dead)
    u16* wqkvT = (u16*)(ws + 176 * MB);    // [1536][512] bf16, 1.5MB (q rows pre-scaled)
    u16* woT  = (u16*)(ws + 177 * MB + 512 * 1024);
    u16* w1T  = (u16*)(ws + 178 * MB);     // [2048][512], 2MB
    u16* w2T  = (u16*)(ws + 180 * MB);     // [512][2048], 2MB
    int* sel = (int*)(ws + 182 * MB);      // 64KB
    unsigned char* validk = (unsigned char*)(ws + 182 * MB + 64 * 1024); // 32KB
    int* flagp = (int*)(ws + 182 * MB + 128 * 1024);
    float* bqkv = (float*)(ws + 182 * MB + 132 * 1024);  // [1536] f32

    detect_kernel<<<1, 256, 0, stream>>>((const u32*)patch, flagp);

    wtrans_all_kernel<<<3072, dim3(32, 8), 0, stream>>>(wq, wk, wv, wo, w1, w2,
        wqkvT, woT, w1T, w2T, flagp);
    prep_bias_kernel<<<6, 256, 0, stream>>>(bq, bk, bv, flagp, bqkv);

    voxsel_kernel<<<NWIN, 64, 0, stream>>>(vpy, vpx, sel);
    ln1_kernel<<<NROW / 4, 256, 0, stream>>>(patch, vox, ln1g, ln1b, sel, flagp, hbuf, validk);

    // fused QKV gemm: N=1536 (q compact/scaled | k | v^T); 6 n-tiles per block (XCD-local A reuse)
    gemm_kernel<<<dim3(2, NROW / 128), 256, 0, stream>>>(hbuf, wqkvT, bqkv,
        qbuf, kbuf, vtt, nullptr, flagp, NROW, 1536, 512, GF_QKV, 512);

    attn_kernel<<<dim3(HEADS, NWIN), 256, 0, stream>>>(qbuf, kbuf, vtt, validk, obuf);

    // x = tokens(patch gather) + o @ wo + bo   (bf16, coalesced staged store)
    gemm_kernel<<<dim3(4, NPATCH / 128), 256, 0, stream>>>(obuf, woT, bo,
        xbuf16, nullptr, nullptr, patch, flagp, NPATCH, 512, 512, GF_RES_PATCH, 512);

    ln2_kernel<<<NPATCH / 4, 256, 0, stream>>>(xbuf16, ln2g, ln2b, flagp, h2buf);

    gemm_kernel<<<dim3(4, NPATCH / 128), 256, 0, stream>>>(h2buf, w1T, b1,
        tbuf, nullptr, nullptr, nullptr, flagp, NPATCH, 2048, 512, GF_GELU, 2048);
    gemm_kernel<<<dim3(4, NPATCH / 128), 256, 0, stream>>>(tbuf, w2T, b2,
        xfbuf, nullptr, nullptr, xbuf16, flagp, NPATCH, 512, 2048, GF_RES_BF16, 512);

    gather_kernel<<<(4096 * 128) / 256, 256, 0, stream>>>(xfbuf, d_out, flagp);
}

// Round 7
// 451.883 us; speedup vs baseline: 1.5646x; 1.5646x over previous
//
#include <hip/hip_runtime.h>
#include <math.h>

using u16 = unsigned short;
using u32 = unsigned int;
using u64 = unsigned long long;
using bf16x8 = __attribute__((ext_vector_type(8))) short;
using f32x4  = __attribute__((ext_vector_type(4))) float;

#define C_DIM   512
#define HEADS   8
#define HDIM    64
#define P_DIM   64
#define A_TOK   256
#define VCAP    256
#define S_TOK   512
#define NWIN    64
#define NROW    32768      // NWIN * S_TOK
#define NPATCH  16384      // NWIN * A_TOK
#define MLP_DIM 2048
#define NV_TOT  2048

__device__ __forceinline__ float bf2f(u16 b) { return __uint_as_float(((u32)b) << 16); }
__device__ __forceinline__ u16 f2bf(float f) {
    u32 u = __float_as_uint(f);
    return (u16)((u + 0x7fffu + ((u >> 16) & 1u)) >> 16);   // RNE
}
__device__ __forceinline__ float4 bf4f(ushort4 v) {
    return make_float4(bf2f(v.x), bf2f(v.y), bf2f(v.z), bf2f(v.w));
}
// dtype-agnostic loads from RAW inputs: isbf=1 -> bf16, else f32
__device__ __forceinline__ float ldf(const void* p, size_t e, int isbf) {
    return isbf ? bf2f(((const u16*)p)[e]) : ((const float*)p)[e];
}
__device__ __forceinline__ float4 ld4(const void* p, size_t e, int isbf) {  // e % 4 == 0
    if (isbf) return bf4f(*(const ushort4*)((const u16*)p + e));
    return *(const float4*)((const float*)p + e);
}
// async global->LDS, 16B per lane; lds dest must be wave-uniform-base + lane*16
__device__ __forceinline__ void gload16(const u16* g, u16* l) {
    __builtin_amdgcn_global_load_lds(
        (const __attribute__((address_space(1))) u32*)g,
        (__attribute__((address_space(3))) u32*)l, 16, 0, 0);
}
// tanh-form GELU via sigmoid: x*sigmoid(1.5957691x + 0.0713548x^3); |err| <= ~3e-4
__device__ __forceinline__ float fast_gelu(float x) {
    float x2 = x * x;
    float z = x * (-1.5957691216f - 0.07135481283f * x2);
    return x / (1.f + __expf(z));
}

// ---------------- dtype detector: vote on low-16-bits-as-bf16 plausibility ----------------
__global__ void detect_kernel(const u32* __restrict__ patch, int* __restrict__ flag)
{
    __shared__ int sm[256];
    int t = threadIdx.x;
    int cnt = 0;
    for (int i = t; i < 4096; i += 256) {
        u32 w = patch[i];
        float v = __uint_as_float((w & 0xffffu) << 16);
        float a = fabsf(v);
        if (a > 1e-8f && a < 1e4f) cnt++;
    }
    sm[t] = cnt;
    __syncthreads();
    for (int o = 128; o; o >>= 1) { if (t < o) sm[t] += sm[t + o]; __syncthreads(); }
    if (t == 0) *flag = (sm[0] > 2458) ? 1 : 0;    // >60% plausible => bf16 world
}

// ------------- merged weight transposes: all six [K][N] -> [N][K] bf16 in one dispatch -------------
__global__ void wtrans_all_kernel(const void* __restrict__ wq, const void* __restrict__ wk,
                                  const void* __restrict__ wv, const void* __restrict__ wo,
                                  const void* __restrict__ w1, const void* __restrict__ w2,
                                  u16* __restrict__ wqkvT, u16* __restrict__ woT,
                                  u16* __restrict__ w1T, u16* __restrict__ w2T,
                                  const int* __restrict__ flagp)
{
    __shared__ u16 tile[32][33];
    int isbf = *flagp;
    int id = blockIdx.x;
    const void* in; u16* out; int K, N; float sc = 1.f;
    if (id < 256)       { in = wq; out = wqkvT;              K = 512;  N = 512;  sc = 0.125f; }
    else if (id < 512)  { id -= 256;  in = wk; out = wqkvT + 512 * 512;  K = 512;  N = 512; }
    else if (id < 768)  { id -= 512;  in = wv; out = wqkvT + 1024 * 512; K = 512;  N = 512; }
    else if (id < 1024) { id -= 768;  in = wo; out = woT;    K = 512;  N = 512; }
    else if (id < 2048) { id -= 1024; in = w1; out = w1T;    K = 512;  N = 2048; }
    else                { id -= 2048; in = w2; out = w2T;    K = 2048; N = 512; }
    int ntx = N >> 5;
    int n0 = (id % ntx) * 32, k0 = (id / ntx) * 32;
    int tx = threadIdx.x, ty = threadIdx.y;   // block (32, 8)
    #pragma unroll
    for (int i = 0; i < 4; i++)
        tile[ty + i * 8][tx] = f2bf(sc * ldf(in, (size_t)(k0 + ty + i * 8) * N + (n0 + tx), isbf));
    __syncthreads();
    #pragma unroll
    for (int i = 0; i < 4; i++)
        out[(size_t)(n0 + ty + i * 8) * K + (k0 + tx)] = tile[tx][ty + i * 8];
}

// ---------------- fused q/k/v bias vector (q part pre-scaled), f32 ----------------
__global__ void prep_bias_kernel(const void* __restrict__ bq, const void* __restrict__ bk,
                                 const void* __restrict__ bv,
                                 const int* __restrict__ flagp, float* __restrict__ bqkv)
{
    int isbf = *flagp;
    int t = blockIdx.x * 256 + threadIdx.x;
    if (t < 512)       bqkv[t] = 0.125f * ldf(bq, t, isbf);
    else if (t < 1024) bqkv[t] = ldf(bk, t - 512, isbf);
    else if (t < 1536) bqkv[t] = ldf(bv, t - 1024, isbf);
}

// ---------------- per-window voxel selection (stable order, cap 256) ----------------
__global__ void voxsel_kernel(const int* __restrict__ vy, const int* __restrict__ vx,
                              int* __restrict__ sel)
{
    int n = blockIdx.x;                 // 64 windows, 64 threads (1 wave)
    int lane = threadIdx.x;
    int y0 = (n >> 3) << 3, x0 = (n & 7) << 3;
    int count = 0;
    for (int base = 0; base < NV_TOT; base += 64) {
        int v = base + lane;
        int yy = vy[v], xx = vx[v];
        bool m = (yy >= y0) && (yy < y0 + 16) && (xx >= x0) && (xx < x0 + 16);
        u64 mask = __ballot(m);
        int pos = count + __popcll(mask & ((1ull << lane) - 1ull));
        if (m && pos < VCAP) sel[n * VCAP + pos] = v;
        count += __popcll(mask);
    }
    for (int j = lane; j < VCAP; j += 64)
        if (j >= count) sel[n * VCAP + j] = -1;
}

// ---------------- gather tokens + LN1 -> h (bf16), validity flags ----------------
__global__ __launch_bounds__(256) void ln1_kernel(
    const void* __restrict__ patch, const void* __restrict__ vox,
    const void* __restrict__ g, const void* __restrict__ b,
    const int* __restrict__ sel, const int* __restrict__ flagp,
    u16* __restrict__ h, unsigned char* __restrict__ validk)
{
    int isbf = *flagp;
    int r = blockIdx.x * 4 + (threadIdx.x >> 6);    // one wave per row
    int lane = threadIdx.x & 63;
    int n = r >> 9, s = r & 511;
    const void* tok = nullptr;
    size_t base = 0;
    bool valid;
    if (s < A_TOK) {
        int wy = s >> 4, wx = s & 15;
        int iy = ((n >> 3) << 3) + wy, ix = ((n & 7) << 3) + wx;
        valid = (iy < P_DIM) && (ix < P_DIM);
        tok = patch; base = (size_t)(iy * P_DIM + ix) * C_DIM;
    } else {
        int idx = sel[n * VCAP + (s - A_TOK)];
        valid = (idx >= 0);
        tok = vox; base = valid ? (size_t)idx * C_DIM : 0;
    }
    float4 xa = make_float4(0.f, 0.f, 0.f, 0.f), xb = xa;
    if (valid) {
        xa = ld4(tok, base + lane * 4, isbf);
        xb = ld4(tok, base + 256 + lane * 4, isbf);
    }
    float sum = xa.x + xa.y + xa.z + xa.w + xb.x + xb.y + xb.z + xb.w;
    float sq  = xa.x * xa.x + xa.y * xa.y + xa.z * xa.z + xa.w * xa.w
              + xb.x * xb.x + xb.y * xb.y + xb.z * xb.z + xb.w * xb.w;
    #pragma unroll
    for (int off = 32; off; off >>= 1) {
        sum += __shfl_xor(sum, off, 64);
        sq  += __shfl_xor(sq,  off, 64);
    }
    float mean = sum * (1.f / C_DIM);
    float var  = fmaxf(sq * (1.f / C_DIM) - mean * mean, 0.f);
    float rstd = rsqrtf(var + 1e-5f);
    float4 ga = ld4(g, lane * 4, isbf);
    float4 gb = ld4(g, 256 + lane * 4, isbf);
    float4 ba = ld4(b, lane * 4, isbf);
    float4 bb = ld4(b, 256 + lane * 4, isbf);
    ushort4 oa, ob;
    oa.x = f2bf((xa.x - mean) * rstd * ga.x + ba.x);
    oa.y = f2bf((xa.y - mean) * rstd * ga.y + ba.y);
    oa.z = f2bf((xa.z - mean) * rstd * ga.z + ba.z);
    oa.w = f2bf((xa.w - mean) * rstd * ga.w + ba.w);
    ob.x = f2bf((xb.x - mean) * rstd * gb.x + bb.x);
    ob.y = f2bf((xb.y - mean) * rstd * gb.y + bb.y);
    ob.z = f2bf((xb.z - mean) * rstd * gb.z + bb.z);
    ob.w = f2bf((xb.w - mean) * rstd * gb.w + bb.w);
    ((ushort4*)(h + (size_t)r * C_DIM))[lane]      = oa;
    ((ushort4*)(h + (size_t)r * C_DIM))[lane + 64] = ob;
    if (lane == 0) validk[r] = valid ? 1 : 0;
}

// ---------------- LN2 over bf16 rows -> bf16 ----------------
__global__ __launch_bounds__(256) void ln2_kernel(
    const u16* __restrict__ x,
    const void* __restrict__ g, const void* __restrict__ b,
    const int* __restrict__ flagp,
    u16* __restrict__ h2)
{
    int isbf = *flagp;
    int r = blockIdx.x * 4 + (threadIdx.x >> 6);
    int lane = threadIdx.x & 63;
    const u16* src = x + (size_t)r * C_DIM;
    float4 xa = bf4f(((const ushort4*)src)[lane]);
    float4 xb = bf4f(((const ushort4*)src)[lane + 64]);
    float sum = xa.x + xa.y + xa.z + xa.w + xb.x + xb.y + xb.z + xb.w;
    float sq  = xa.x * xa.x + xa.y * xa.y + xa.z * xa.z + xa.w * xa.w
              + xb.x * xb.x + xb.y * xb.y + xb.z * xb.z + xb.w * xb.w;
    #pragma unroll
    for (int off = 32; off; off >>= 1) {
        sum += __shfl_xor(sum, off, 64);
        sq  += __shfl_xor(sq,  off, 64);
    }
    float mean = sum * (1.f / C_DIM);
    float var  = fmaxf(sq * (1.f / C_DIM) - mean * mean, 0.f);
    float rstd = rsqrtf(var + 1e-5f);
    float4 ga = ld4(g, lane * 4, isbf);
    float4 gb = ld4(g, 256 + lane * 4, isbf);
    float4 ba = ld4(b, lane * 4, isbf);
    float4 bb = ld4(b, 256 + lane * 4, isbf);
    ushort4 oa, ob;
    oa.x = f2bf((xa.x - mean) * rstd * ga.x + ba.x);
    oa.y = f2bf((xa.y - mean) * rstd * ga.y + ba.y);
    oa.z = f2bf((xa.z - mean) * rstd * ga.z + ba.z);
    oa.w = f2bf((xa.w - mean) * rstd * ga.w + ba.w);
    ob.x = f2bf((xb.x - mean) * rstd * gb.x + bb.x);
    ob.y = f2bf((xb.y - mean) * rstd * gb.y + bb.y);
    ob.z = f2bf((xb.z - mean) * rstd * gb.z + bb.z);
    ob.w = f2bf((xb.w - mean) * rstd * gb.w + bb.w);
    ((ushort4*)(h2 + (size_t)r * C_DIM))[lane]      = oa;
    ((ushort4*)(h2 + (size_t)r * C_DIM))[lane + 64] = ob;
}

// ---------------- generic bf16 MFMA GEMM: C = op(A @ B^T + bias), one tile/block ----------------
#define GF_GELU      2
#define GF_RES_BF16  8    // += res (bf16, [M][N])
#define GF_RES_PATCH 16   // += gathered patch token (raw dtype), valid positions only
#define GF_QKV       32   // N=1536: cols 0-511 q (compact, patch rows), 512-1023 k, 1024-1535 v^T
                          // + XCD-local block remap (12 n-tiles of one m-tile on one XCD)

__global__ __launch_bounds__(256) void gemm_kernel(
    const u16* __restrict__ A, const u16* __restrict__ BT,
    const void* __restrict__ bias,
    void* __restrict__ Cout, void* __restrict__ Cout2, void* __restrict__ Cout3,
    const void* __restrict__ resv,
    const int* __restrict__ flagp,
    int M, int N, int K, int flags, int ldc)
{
    __shared__ u16 smem[2 * 128 * 64];   // As = smem, Bs = smem+8192 (u16); epilogue stage reuse
    int tid = threadIdx.x;
    int nt, mt;
    if (flags & GF_QKV) {
        // XCD-local remap: linear id L (x fastest), xcd = L % 8 (round-robin heuristic).
        // All 12 n-tiles of m-tile m land on XCD m/32 in adjacent slots -> A fetched into 1 L2.
        int L = blockIdx.x + 12 * blockIdx.y;
        int c = L & 7, s = L >> 3;            // s in [0,384)
        mt = c * 32 + s / 12;
        nt = s % 12;
    } else { nt = blockIdx.x; mt = blockIdx.y; }
    int m0 = mt << 7, n0 = nt << 7;
    int region = (flags & GF_QKV) ? (nt >> 2) : 0;   // 0:q 1:k 2:v^T
    if ((flags & GF_QKV) && region == 0 && (m0 & 511) >= 256) return;  // voxel rows need no Q
    int isbf = *flagp;
    int w = tid >> 6, lane = tid & 63;
    int wr = (w >> 1) * 64, wc = (w & 1) * 64;
    int l16 = lane & 15, quad = lane >> 4;
    u16* As = smem;
    u16* Bs = smem + 8192;
    bool vtb = (flags & GF_QKV) && (region == 2);   // transposed-output block

    f32x4 acc[4][4];
    #pragma unroll
    for (int i = 0; i < 4; i++)
        #pragma unroll
        for (int j = 0; j < 4; j++) { acc[i][j][0] = 0.f; acc[i][j][1] = 0.f; acc[i][j][2] = 0.f; acc[i][j][3] = 0.f; }

    int swz = (l16 & 7);                   // frag-read chunk swizzle key
    const u16* Xs = vtb ? Bs : As;         // first operand rows -> D rows
    const u16* Ys = vtb ? As : Bs;
    for (int k0 = 0; k0 < K; k0 += 64) {
        #pragma unroll
        for (int it = 0; it < 4; it++) {
            int c = (it * 4 + w) * 64 + lane;   // 0..1023 chunk slots
            int row = c >> 3, phys = c & 7;
            int kc = phys ^ (row & 7);          // XOR swizzle: break 128B-stride bank aliasing
            gload16(A  + (size_t)(m0 + row) * K + k0 + kc * 8, As + (size_t)c * 8);
            gload16(BT + (size_t)(n0 + row) * K + k0 + kc * 8, Bs + (size_t)c * 8);
        }
        __syncthreads();
        #pragma unroll
        for (int ks = 0; ks < 2; ks++) {
            bf16x8 a[4], b[4];
            #pragma unroll
            for (int i = 0; i < 4; i++) {
                int chunk = (ks * 4 + quad) ^ swz;
                a[i] = *(const bf16x8*)&Xs[(wr + i * 16 + l16) * 64 + chunk * 8];
            }
            #pragma unroll
            for (int j = 0; j < 4; j++) {
                int chunk = (ks * 4 + quad) ^ swz;
                b[j] = *(const bf16x8*)&Ys[(wc + j * 16 + l16) * 64 + chunk * 8];
            }
            #pragma unroll
            for (int i = 0; i < 4; i++)
                #pragma unroll
                for (int j = 0; j < 4; j++)
                    acc[i][j] = __builtin_amdgcn_mfma_f32_16x16x32_bf16(a[i], b[j], acc[i][j], 0, 0, 0);
        }
        __syncthreads();
    }

    // ---------- epilogue (bf16, LDS-staged, coalesced 128B rows) ----------
    u16* st = smem + w * 4096;          // per-wave 64x64 bf16 stage (reuses tile LDS)
    #pragma unroll
    for (int i = 0; i < 4; i++) {
        #pragma unroll
        for (int j = 0; j < 4; j++) {
            int gcol = n0 + wc + j * 16 + l16;
            float bc = 0.f;
            if (flags & GF_QKV) { if (!vtb) bc = ((const float*)bias)[gcol]; }
            else if (bias) bc = ldf(bias, gcol, isbf);
            #pragma unroll
            for (int r2 = 0; r2 < 4; r2++) {
                int lrow = wr + i * 16 + quad * 4 + r2;
                int grow = m0 + lrow;
                if (vtb) bc = ((const float*)bias)[n0 + lrow];   // channel-indexed bias
                float v = acc[i][j][r2] + bc;
                if (flags & GF_GELU) v = fast_gelu(v);
                if (flags & GF_RES_BF16) v += bf2f(((const u16*)resv)[(size_t)grow * N + gcol]);
                if (flags & GF_RES_PATCH) {
                    int nn = grow >> 8, s = grow & 255;
                    int iy = ((nn >> 3) << 3) + (s >> 4);
                    int ix = ((nn & 7) << 3) + (s & 15);
                    if (iy < P_DIM && ix < P_DIM)
                        v += ldf(resv, (size_t)(iy * P_DIM + ix) * C_DIM + gcol, isbf);
                }
                st[(i * 16 + quad * 4 + r2) * 64 + j * 16 + l16] = f2bf(v);
            }
        }
    }
    asm volatile("" ::: "memory");   // same-wave LDS: block reorder, no barrier needed
    u16* cdst; int cst;
    if (flags & GF_QKV) {
        if (region == 0) {          // q: compact patch rows, pre-scaled
            cst = 512;
            cdst = (u16*)Cout  + (size_t)(((m0 >> 9) << 8) + (m0 & 255) + wr) * 512 + (n0 + wc);
        } else if (region == 1) {   // k
            cst = 512;
            cdst = (u16*)Cout2 + (size_t)(m0 + wr) * 512 + (n0 - 512 + wc);
        } else {                    // v^T: rows = channels, cols = tokens
            cst = NROW;
            cdst = (u16*)Cout3 + (size_t)(n0 - 1024 + wr) * NROW + (m0 + wc);
        }
    } else {
        cst = ldc;
        cdst = (u16*)Cout + (size_t)(m0 + wr) * ldc + (n0 + wc);
    }
    #pragma unroll
    for (int rr = 0; rr < 8; rr++) {
        int row = rr * 8 + (lane >> 3);
        uint4 val = *(const uint4*)&st[row * 64 + (lane & 7) * 8];
        *(uint4*)(cdst + (size_t)row * cst + (lane & 7) * 8) = val;   // 128B/row coalesced
    }
}

// ---------------- flash attention per (window, head); patch queries only ----------------
__global__ __launch_bounds__(256) void attn_kernel(
    const u16* __restrict__ q, const u16* __restrict__ k, const u16* __restrict__ vtg,
    const unsigned char* __restrict__ validk,
    u16* __restrict__ o)
{
    __shared__ u16 sK[64 * 64];          // [key][d], DMA-staged, swizzled chunks
    __shared__ u16 sV[64 * 64];          // [d][key], DMA-staged from V^T, swizzled chunks
    __shared__ u16 sP[4 * 64 * 64];      // per-wave P tile, chunk-swizzled (48KB total LDS)
    int h = blockIdx.x, n = blockIdx.y;
    int tid = threadIdx.x;
    int w = tid >> 6, lane = tid & 63;
    int l16 = lane & 15, quad = lane >> 4;
    int swz = (l16 & 7);

    bf16x8 qf[4][2];
    #pragma unroll
    for (int i = 0; i < 4; i++)
        #pragma unroll
        for (int ks = 0; ks < 2; ks++) {
            int row = n * A_TOK + w * 64 + i * 16 + l16;       // compact q
            int col = h * HDIM + ks * 32 + quad * 8;
            qf[i][ks] = *(const bf16x8*)(q + (size_t)row * C_DIM + col);
        }

    f32x4 oacc[4][4];
    float lsum[4][4];
    #pragma unroll
    for (int i = 0; i < 4; i++)
        #pragma unroll
        for (int j = 0; j < 4; j++) {
            oacc[i][j][0] = 0.f; oacc[i][j][1] = 0.f; oacc[i][j][2] = 0.f; oacc[i][j][3] = 0.f;
            lsum[i][j] = 0.f;
        }

    for (int ktile = 0; ktile < 8; ktile++) {
        __syncthreads();                       // prior tile's readers done before overwrite
        #pragma unroll
        for (int it = 0; it < 2; it++) {
            int c = it * 256 + w * 64 + lane;  // 0..511 chunk slots
            int row = c >> 3, phys = c & 7;
            int kc = phys ^ (row & 7);
            int grow = n * S_TOK + ktile * 64 + row;
            gload16(k + (size_t)grow * C_DIM + h * HDIM + kc * 8, sK + (size_t)c * 8);
            gload16(vtg + (size_t)(h * HDIM + row) * (size_t)NROW + n * S_TOK + ktile * 64 + kc * 8,
                    sV + (size_t)c * 8);
        }
        __syncthreads();

        f32x4 sacc[4][4];
        #pragma unroll
        for (int i = 0; i < 4; i++)
            #pragma unroll
            for (int j = 0; j < 4; j++) { sacc[i][j][0] = 0.f; sacc[i][j][1] = 0.f; sacc[i][j][2] = 0.f; sacc[i][j][3] = 0.f; }
        #pragma unroll
        for (int ks = 0; ks < 2; ks++) {
            int chunk = (ks * 4 + quad) ^ swz;
            bf16x8 bfr[4];
            #pragma unroll
            for (int j = 0; j < 4; j++) bfr[j] = *(const bf16x8*)&sK[(j * 16 + l16) * 64 + chunk * 8];
            #pragma unroll
            for (int i = 0; i < 4; i++)
                #pragma unroll
                for (int j = 0; j < 4; j++)
                    sacc[i][j] = __builtin_amdgcn_mfma_f32_16x16x32_bf16(qf[i][ks], bfr[j], sacc[i][j], 0, 0, 0);
        }

        bool kvalid[4];
        #pragma unroll
        for (int j = 0; j < 4; j++)
            kvalid[j] = validk[n * S_TOK + ktile * 64 + j * 16 + l16] != 0;

        #pragma unroll
        for (int i = 0; i < 4; i++)
            #pragma unroll
            for (int r2 = 0; r2 < 4; r2++) {
                int prow = i * 16 + quad * 4 + r2;
                #pragma unroll
                for (int j = 0; j < 4; j++) {
                    float p = kvalid[j] ? __expf(sacc[i][j][r2]) : 0.f;
                    lsum[i][r2] += p;
                    int col = j * 16 + l16;
                    int chunk = (col >> 3) ^ (prow & 7);
                    sP[(w * 64 + prow) * 64 + chunk * 8 + (col & 7)] = f2bf(p);
                }
            }
        asm volatile("" ::: "memory");   // per-wave LDS: forbid read-before-write reorder
        #pragma unroll
        for (int ks = 0; ks < 2; ks++) {
            int chunk = (ks * 4 + quad) ^ swz;
            bf16x8 pa[4], vb[4];
            #pragma unroll
            for (int i = 0; i < 4; i++)   pa[i]  = *(const bf16x8*)&sP[(w * 64 + i * 16 + l16) * 64 + chunk * 8];
            #pragma unroll
            for (int jd = 0; jd < 4; jd++) vb[jd] = *(const bf16x8*)&sV[(jd * 16 + l16) * 64 + chunk * 8];
            #pragma unroll
            for (int i = 0; i < 4; i++)
                #pragma unroll
                for (int jd = 0; jd < 4; jd++)
                    oacc[i][jd] = __builtin_amdgcn_mfma_f32_16x16x32_bf16(pa[i], vb[jd], oacc[i][jd], 0, 0, 0);
        }
    }

    // normalize, stage O per-wave in LDS, coalesced 128B stores
    asm volatile("" ::: "memory");
    u16* ost = sP + w * 4096;            // flat 64x64 region, stride 64 (sP data dead)
    #pragma unroll
    for (int i = 0; i < 4; i++) {
        #pragma unroll
        for (int r2 = 0; r2 < 4; r2++) {
            float l = lsum[i][r2];
            #pragma unroll
            for (int off = 8; off; off >>= 1)
                l += __shfl_xor(l, off, 64);
            float inv = (l > 0.f) ? 1.f / l : 0.f;
            #pragma unroll
            for (int jd = 0; jd < 4; jd++)
                ost[(i * 16 + quad * 4 + r2) * 64 + jd * 16 + l16] = f2bf(oacc[i][jd][r2] * inv);
        }
    }
    asm volatile("" ::: "memory");
    u16* obase = o + (size_t)(n * A_TOK + w * 64) * C_DIM + h * HDIM;
    #pragma unroll
    for (int rr = 0; rr < 8; rr++) {
        int row = rr * 8 + (lane >> 3);
        uint4 val = *(const uint4*)&ost[row * 64 + (lane & 7) * 8];
        *(uint4*)(obase + (size_t)row * C_DIM + (lane & 7) * 8) = val;
    }
}

// ---------------- final gather-average (bf16 input) ----------------
__global__ __launch_bounds__(256) void gather_kernel(const u16* __restrict__ xf,
                                                     void* __restrict__ out,
                                                     const int* __restrict__ flagp)
{
    int isbf = *flagp;
    int gid = blockIdx.x * 256 + threadIdx.x;    // pixel*128 + 4-elem chunk
    int p = gid >> 7, cv = gid & 127;
    int py = p >> 6, px = p & 63;
    float4 acc = make_float4(0.f, 0.f, 0.f, 0.f);
    int cnt = 0;
    #pragma unroll
    for (int dy = 0; dy < 2; dy++) {
        int y0 = ((py >> 3) - dy) << 3;
        if (y0 < 0) continue;
        #pragma unroll
        for (int dx = 0; dx < 2; dx++) {
            int x0 = ((px >> 3) - dx) << 3;
            if (x0 < 0) continue;
            int n = ((y0 >> 3) << 3) + (x0 >> 3);
            int s = (py - y0) * 16 + (px - x0);
            float4 t = bf4f(((const ushort4*)(xf + (size_t)(n * A_TOK + s) * C_DIM))[cv]);
            acc.x += t.x; acc.y += t.y; acc.z += t.z; acc.w += t.w;
            cnt++;
        }
    }
    float inv = 1.f / (float)cnt;
    acc.x *= inv; acc.y *= inv; acc.z *= inv; acc.w *= inv;
    if (isbf) {
        ushort4 o;
        o.x = f2bf(acc.x); o.y = f2bf(acc.y); o.z = f2bf(acc.z); o.w = f2bf(acc.w);
        ((ushort4*)out)[gid] = o;
    } else {
        ((float4*)out)[gid] = acc;
    }
}

extern "C" void kernel_launch(void* const* d_in, const int* in_sizes, int n_in,
                              void* d_out, int out_size, void* d_ws, size_t ws_size,
                              hipStream_t stream)
{
    const void* patch = d_in[0];
    const void* vox   = d_in[1];
    const void* ln1g  = d_in[2];
    const void* ln1b  = d_in[3];
    const void* wq = d_in[4];  const void* bq = d_in[5];
    const void* wk = d_in[6];  const void* bk = d_in[7];
    const void* wv = d_in[8];  const void* bv = d_in[9];
    const void* wo = d_in[10]; const void* bo = d_in[11];
    const void* ln2g = d_in[12];
    const void* ln2b = d_in[13];
    const void* w1 = d_in[14]; const void* b1 = d_in[15];
    const void* w2 = d_in[16]; const void* b2 = d_in[17];
    const int* vpy = (const int*)d_in[18];
    const int* vpx = (const int*)d_in[19];

    const size_t MB = 1ull << 20;
    char* ws = (char*)d_ws;
    if (ws_size < 183 * MB) return;   // insufficient workspace -> visible failure

    u16*  hbuf  = (u16*)(ws + 0);          // [32768][512] bf16, 32MB
    u16*  kbuf  = (u16*)(ws + 32 * MB);    // [32768][512] bf16, 32MB
    u16*  vtt   = (u16*)(ws + 64 * MB);    // V^T [512][32768] bf16, 32MB
    u16*  qbuf  = (u16*)(ws + 96 * MB);    // [16384][512] bf16, 16MB (compact patch)
    u16*  obuf  = (u16*)(ws + 112 * MB);   // 16MB
    u16*  xbuf16 = (u16*)(ws + 128 * MB);  // x residual [16384][512] bf16, 16MB
    u16*  h2buf = (u16*)(ws + 160 * MB);   // 16MB
    u16*  tbuf  = (u16*)(ws + 0);          // [16384][2048] bf16, 64MB (reuse h+k, dead)
    u16*  xfbuf = (u16*)(ws + 64 * MB);    // [16384][512] bf16, 16MB (reuse vtt, dead)
    u16* wqkvT = (u16*)(ws + 176 * MB);    // [1536][512] bf16, 1.5MB (q rows pre-scaled)
    u16* woT  = (u16*)(ws + 177 * MB + 512 * 1024);
    u16* w1T  = (u16*)(ws + 178 * MB);     // [2048][512], 2MB
    u16* w2T  = (u16*)(ws + 180 * MB);     // [512][2048], 2MB
    int* sel = (int*)(ws + 182 * MB);      // 64KB
    unsigned char* validk = (unsigned char*)(ws + 182 * MB + 64 * 1024); // 32KB
    int* flagp = (int*)(ws + 182 * MB + 128 * 1024);
    float* bqkv = (float*)(ws + 182 * MB + 132 * 1024);  // [1536] f32

    detect_kernel<<<1, 256, 0, stream>>>((const u32*)patch, flagp);

    wtrans_all_kernel<<<3072, dim3(32, 8), 0, stream>>>(wq, wk, wv, wo, w1, w2,
        wqkvT, woT, w1T, w2T, flagp);
    prep_bias_kernel<<<6, 256, 0, stream>>>(bq, bk, bv, flagp, bqkv);

    voxsel_kernel<<<NWIN, 64, 0, stream>>>(vpy, vpx, sel);
    ln1_kernel<<<NROW / 4, 256, 0, stream>>>(patch, vox, ln1g, ln1b, sel, flagp, hbuf, validk);

    // fused QKV gemm: one tile/block, XCD-local remap inside kernel
    gemm_kernel<<<dim3(12, NROW / 128), 256, 0, stream>>>(hbuf, wqkvT, bqkv,
        qbuf, kbuf, vtt, nullptr, flagp, NROW, 1536, 512, GF_QKV, 512);

    attn_kernel<<<dim3(HEADS, NWIN), 256, 0, stream>>>(qbuf, kbuf, vtt, validk, obuf);

    // x = tokens(patch gather) + o @ wo + bo   (bf16, coalesced staged store)
    gemm_kernel<<<dim3(4, NPATCH / 128), 256, 0, stream>>>(obuf, woT, bo,
        xbuf16, nullptr, nullptr, patch, flagp, NPATCH, 512, 512, GF_RES_PATCH, 512);

    ln2_kernel<<<NPATCH / 4, 256, 0, stream>>>(xbuf16, ln2g, ln2b, flagp, h2buf);

    gemm_kernel<<<dim3(16, NPATCH / 128), 256, 0, stream>>>(h2buf, w1T, b1,
        tbuf, nullptr, nullptr, nullptr, flagp, NPATCH, 2048, 512, GF_GELU, 2048);
    gemm_kernel<<<dim3(4, NPATCH / 128), 256, 0, stream>>>(tbuf, w2T, b2,
        xfbuf, nullptr, nullptr, xbuf16, flagp, NPATCH, 512, 2048, GF_RES_BF16, 512);

    gather_kernel<<<(4096 * 128) / 256, 256, 0, stream>>>(xfbuf, d_out, flagp);
}

// Round 8
// 446.309 us; speedup vs baseline: 1.5842x; 1.0125x over previous
//
#include <hip/hip_runtime.h>
#include <math.h>

using u16 = unsigned short;
using u32 = unsigned int;
using u64 = unsigned long long;
using bf16x8 = __attribute__((ext_vector_type(8))) short;
using f32x4  = __attribute__((ext_vector_type(4))) float;

#define C_DIM   512
#define HEADS   8
#define HDIM    64
#define P_DIM   64
#define A_TOK   256
#define VCAP    256
#define S_TOK   512
#define NWIN    64
#define NROW    32768      // NWIN * S_TOK
#define NPATCH  16384      // NWIN * A_TOK
#define MLP_DIM 2048
#define NV_TOT  2048

__device__ __forceinline__ float bf2f(u16 b) { return __uint_as_float(((u32)b) << 16); }
__device__ __forceinline__ u16 f2bf(float f) {
    u32 u = __float_as_uint(f);
    return (u16)((u + 0x7fffu + ((u >> 16) & 1u)) >> 16);   // RNE
}
__device__ __forceinline__ float4 bf4f(ushort4 v) {
    return make_float4(bf2f(v.x), bf2f(v.y), bf2f(v.z), bf2f(v.w));
}
// dtype-agnostic loads from RAW inputs: isbf=1 -> bf16, else f32
__device__ __forceinline__ float ldf(const void* p, size_t e, int isbf) {
    return isbf ? bf2f(((const u16*)p)[e]) : ((const float*)p)[e];
}
__device__ __forceinline__ float4 ld4(const void* p, size_t e, int isbf) {  // e % 4 == 0
    if (isbf) return bf4f(*(const ushort4*)((const u16*)p + e));
    return *(const float4*)((const float*)p + e);
}
// async global->LDS, 16B per lane; lds dest must be wave-uniform-base + lane*16
__device__ __forceinline__ void gload16(const u16* g, u16* l) {
    __builtin_amdgcn_global_load_lds(
        (const __attribute__((address_space(1))) u32*)g,
        (__attribute__((address_space(3))) u32*)l, 16, 0, 0);
}
// tanh-form GELU via sigmoid: x*sigmoid(1.5957691x + 0.0713548x^3); |err| <= ~3e-4
__device__ __forceinline__ float fast_gelu(float x) {
    float x2 = x * x;
    float z = x * (-1.5957691216f - 0.07135481283f * x2);
    return x / (1.f + __expf(z));
}

// ---------------- dtype detector: vote on low-16-bits-as-bf16 plausibility ----------------
__global__ void detect_kernel(const u32* __restrict__ patch, int* __restrict__ flag)
{
    __shared__ int sm[256];
    int t = threadIdx.x;
    int cnt = 0;
    for (int i = t; i < 4096; i += 256) {
        u32 w = patch[i];
        float v = __uint_as_float((w & 0xffffu) << 16);
        float a = fabsf(v);
        if (a > 1e-8f && a < 1e4f) cnt++;
    }
    sm[t] = cnt;
    __syncthreads();
    for (int o = 128; o; o >>= 1) { if (t < o) sm[t] += sm[t + o]; __syncthreads(); }
    if (t == 0) *flag = (sm[0] > 2458) ? 1 : 0;    // >60% plausible => bf16 world
}

// ------------- merged weight transposes: all six [K][N] -> [N][K] bf16 in one dispatch -------------
__global__ void wtrans_all_kernel(const void* __restrict__ wq, const void* __restrict__ wk,
                                  const void* __restrict__ wv, const void* __restrict__ wo,
                                  const void* __restrict__ w1, const void* __restrict__ w2,
                                  u16* __restrict__ wqkvT, u16* __restrict__ woT,
                                  u16* __restrict__ w1T, u16* __restrict__ w2T,
                                  const int* __restrict__ flagp)
{
    __shared__ u16 tile[32][33];
    int isbf = *flagp;
    int id = blockIdx.x;
    const void* in; u16* out; int K, N; float sc = 1.f;
    if (id < 256)       { in = wq; out = wqkvT;              K = 512;  N = 512;  sc = 0.125f; }
    else if (id < 512)  { id -= 256;  in = wk; out = wqkvT + 512 * 512;  K = 512;  N = 512; }
    else if (id < 768)  { id -= 512;  in = wv; out = wqkvT + 1024 * 512; K = 512;  N = 512; }
    else if (id < 1024) { id -= 768;  in = wo; out = woT;    K = 512;  N = 512; }
    else if (id < 2048) { id -= 1024; in = w1; out = w1T;    K = 512;  N = 2048; }
    else                { id -= 2048; in = w2; out = w2T;    K = 2048; N = 512; }
    int ntx = N >> 5;
    int n0 = (id % ntx) * 32, k0 = (id / ntx) * 32;
    int tx = threadIdx.x, ty = threadIdx.y;   // block (32, 8)
    #pragma unroll
    for (int i = 0; i < 4; i++)
        tile[ty + i * 8][tx] = f2bf(sc * ldf(in, (size_t)(k0 + ty + i * 8) * N + (n0 + tx), isbf));
    __syncthreads();
    #pragma unroll
    for (int i = 0; i < 4; i++)
        out[(size_t)(n0 + ty + i * 8) * K + (k0 + tx)] = tile[tx][ty + i * 8];
}

// ---------------- fused q/k/v bias vector (q part pre-scaled), f32 ----------------
__global__ void prep_bias_kernel(const void* __restrict__ bq, const void* __restrict__ bk,
                                 const void* __restrict__ bv,
                                 const int* __restrict__ flagp, float* __restrict__ bqkv)
{
    int isbf = *flagp;
    int t = blockIdx.x * 256 + threadIdx.x;
    if (t < 512)       bqkv[t] = 0.125f * ldf(bq, t, isbf);
    else if (t < 1024) bqkv[t] = ldf(bk, t - 512, isbf);
    else if (t < 1536) bqkv[t] = ldf(bv, t - 1024, isbf);
}

// ---------------- per-window voxel selection (stable order, cap 256) ----------------
__global__ void voxsel_kernel(const int* __restrict__ vy, const int* __restrict__ vx,
                              int* __restrict__ sel)
{
    int n = blockIdx.x;                 // 64 windows, 64 threads (1 wave)
    int lane = threadIdx.x;
    int y0 = (n >> 3) << 3, x0 = (n & 7) << 3;
    int count = 0;
    for (int base = 0; base < NV_TOT; base += 64) {
        int v = base + lane;
        int yy = vy[v], xx = vx[v];
        bool m = (yy >= y0) && (yy < y0 + 16) && (xx >= x0) && (xx < x0 + 16);
        u64 mask = __ballot(m);
        int pos = count + __popcll(mask & ((1ull << lane) - 1ull));
        if (m && pos < VCAP) sel[n * VCAP + pos] = v;
        count += __popcll(mask);
    }
    for (int j = lane; j < VCAP; j += 64)
        if (j >= count) sel[n * VCAP + j] = -1;
}

// ---------------- gather tokens + LN1 -> h (bf16), validity flags ----------------
__global__ __launch_bounds__(256) void ln1_kernel(
    const void* __restrict__ patch, const void* __restrict__ vox,
    const void* __restrict__ g, const void* __restrict__ b,
    const int* __restrict__ sel, const int* __restrict__ flagp,
    u16* __restrict__ h, unsigned char* __restrict__ validk)
{
    int isbf = *flagp;
    int r = blockIdx.x * 4 + (threadIdx.x >> 6);    // one wave per row
    int lane = threadIdx.x & 63;
    int n = r >> 9, s = r & 511;
    const void* tok = nullptr;
    size_t base = 0;
    bool valid;
    if (s < A_TOK) {
        int wy = s >> 4, wx = s & 15;
        int iy = ((n >> 3) << 3) + wy, ix = ((n & 7) << 3) + wx;
        valid = (iy < P_DIM) && (ix < P_DIM);
        tok = patch; base = (size_t)(iy * P_DIM + ix) * C_DIM;
    } else {
        int idx = sel[n * VCAP + (s - A_TOK)];
        valid = (idx >= 0);
        tok = vox; base = valid ? (size_t)idx * C_DIM : 0;
    }
    float4 xa = make_float4(0.f, 0.f, 0.f, 0.f), xb = xa;
    if (valid) {
        xa = ld4(tok, base + lane * 4, isbf);
        xb = ld4(tok, base + 256 + lane * 4, isbf);
    }
    float sum = xa.x + xa.y + xa.z + xa.w + xb.x + xb.y + xb.z + xb.w;
    float sq  = xa.x * xa.x + xa.y * xa.y + xa.z * xa.z + xa.w * xa.w
              + xb.x * xb.x + xb.y * xb.y + xb.z * xb.z + xb.w * xb.w;
    #pragma unroll
    for (int off = 32; off; off >>= 1) {
        sum += __shfl_xor(sum, off, 64);
        sq  += __shfl_xor(sq,  off, 64);
    }
    float mean = sum * (1.f / C_DIM);
    float var  = fmaxf(sq * (1.f / C_DIM) - mean * mean, 0.f);
    float rstd = rsqrtf(var + 1e-5f);
    float4 ga = ld4(g, lane * 4, isbf);
    float4 gb = ld4(g, 256 + lane * 4, isbf);
    float4 ba = ld4(b, lane * 4, isbf);
    float4 bb = ld4(b, 256 + lane * 4, isbf);
    ushort4 oa, ob;
    oa.x = f2bf((xa.x - mean) * rstd * ga.x + ba.x);
    oa.y = f2bf((xa.y - mean) * rstd * ga.y + ba.y);
    oa.z = f2bf((xa.z - mean) * rstd * ga.z + ba.z);
    oa.w = f2bf((xa.w - mean) * rstd * ga.w + ba.w);
    ob.x = f2bf((xb.x - mean) * rstd * gb.x + bb.x);
    ob.y = f2bf((xb.y - mean) * rstd * gb.y + bb.y);
    ob.z = f2bf((xb.z - mean) * rstd * gb.z + bb.z);
    ob.w = f2bf((xb.w - mean) * rstd * gb.w + bb.w);
    ((ushort4*)(h + (size_t)r * C_DIM))[lane]      = oa;
    ((ushort4*)(h + (size_t)r * C_DIM))[lane + 64] = ob;
    if (lane == 0) validk[r] = valid ? 1 : 0;
}

// ---------------- LN2 over bf16 rows -> bf16 ----------------
__global__ __launch_bounds__(256) void ln2_kernel(
    const u16* __restrict__ x,
    const void* __restrict__ g, const void* __restrict__ b,
    const int* __restrict__ flagp,
    u16* __restrict__ h2)
{
    int isbf = *flagp;
    int r = blockIdx.x * 4 + (threadIdx.x >> 6);
    int lane = threadIdx.x & 63;
    const u16* src = x + (size_t)r * C_DIM;
    float4 xa = bf4f(((const ushort4*)src)[lane]);
    float4 xb = bf4f(((const ushort4*)src)[lane + 64]);
    float sum = xa.x + xa.y + xa.z + xa.w + xb.x + xb.y + xb.z + xb.w;
    float sq  = xa.x * xa.x + xa.y * xa.y + xa.z * xa.z + xa.w * xa.w
              + xb.x * xb.x + xb.y * xb.y + xb.z * xb.z + xb.w * xb.w;
    #pragma unroll
    for (int off = 32; off; off >>= 1) {
        sum += __shfl_xor(sum, off, 64);
        sq  += __shfl_xor(sq,  off, 64);
    }
    float mean = sum * (1.f / C_DIM);
    float var  = fmaxf(sq * (1.f / C_DIM) - mean * mean, 0.f);
    float rstd = rsqrtf(var + 1e-5f);
    float4 ga = ld4(g, lane * 4, isbf);
    float4 gb = ld4(g, 256 + lane * 4, isbf);
    float4 ba = ld4(b, lane * 4, isbf);
    float4 bb = ld4(b, 256 + lane * 4, isbf);
    ushort4 oa, ob;
    oa.x = f2bf((xa.x - mean) * rstd * ga.x + ba.x);
    oa.y = f2bf((xa.y - mean) * rstd * ga.y + ba.y);
    oa.z = f2bf((xa.z - mean) * rstd * ga.z + ba.z);
    oa.w = f2bf((xa.w - mean) * rstd * ga.w + ba.w);
    ob.x = f2bf((xb.x - mean) * rstd * gb.x + bb.x);
    ob.y = f2bf((xb.y - mean) * rstd * gb.y + bb.y);
    ob.z = f2bf((xb.z - mean) * rstd * gb.z + bb.z);
    ob.w = f2bf((xb.w - mean) * rstd * gb.w + bb.w);
    ((ushort4*)(h2 + (size_t)r * C_DIM))[lane]      = oa;
    ((ushort4*)(h2 + (size_t)r * C_DIM))[lane + 64] = ob;
}

// ---------------- generic bf16 MFMA GEMM: C = op(A @ B^T + bias), one tile/block ----------------
// XCD-local block remap for ALL dispatches (gridDim.y % 8 == 0): all gridDim.x n-tiles of an
// m-tile run adjacently on one XCD (xcd = linear_id % 8 heuristic) -> A-tile hits one L2.
#define GF_GELU      2
#define GF_RES_BF16  8    // += res (bf16, [M][N])
#define GF_RES_PATCH 16   // += gathered patch token (raw dtype), valid positions only
#define GF_QKV       32   // N=1536: cols 0-511 q (compact, patch rows), 512-1023 k, 1024-1535 v^T

__global__ __launch_bounds__(256) void gemm_kernel(
    const u16* __restrict__ A, const u16* __restrict__ BT,
    const void* __restrict__ bias,
    void* __restrict__ Cout, void* __restrict__ Cout2, void* __restrict__ Cout3,
    const void* __restrict__ resv,
    const int* __restrict__ flagp,
    int M, int N, int K, int flags, int ldc)
{
    __shared__ u16 smem[2 * 128 * 64];   // As = smem, Bs = smem+8192 (u16); epilogue stage reuse
    int tid = threadIdx.x;
    int nt, mt;
    int gx = gridDim.x, gy = gridDim.y;
    if ((gy & 7) == 0) {
        // XCD-local remap: linear id L (x fastest), xcd = L % 8 (round-robin heuristic).
        int L = blockIdx.x + gx * blockIdx.y;
        int c = L & 7, s = L >> 3;
        mt = c * (gy >> 3) + s / gx;
        nt = s % gx;
    } else { nt = blockIdx.x; mt = blockIdx.y; }
    int m0 = mt << 7, n0 = nt << 7;
    int region = (flags & GF_QKV) ? (nt >> 2) : 0;   // 0:q 1:k 2:v^T
    if ((flags & GF_QKV) && region == 0 && (m0 & 511) >= 256) return;  // voxel rows need no Q
    int isbf = *flagp;
    int w = tid >> 6, lane = tid & 63;
    int wr = (w >> 1) * 64, wc = (w & 1) * 64;
    int l16 = lane & 15, quad = lane >> 4;
    u16* As = smem;
    u16* Bs = smem + 8192;
    bool vtb = (flags & GF_QKV) && (region == 2);   // transposed-output block

    f32x4 acc[4][4];
    #pragma unroll
    for (int i = 0; i < 4; i++)
        #pragma unroll
        for (int j = 0; j < 4; j++) { acc[i][j][0] = 0.f; acc[i][j][1] = 0.f; acc[i][j][2] = 0.f; acc[i][j][3] = 0.f; }

    int swz = (l16 & 7);                   // frag-read chunk swizzle key
    const u16* Xs = vtb ? Bs : As;         // first operand rows -> D rows
    const u16* Ys = vtb ? As : Bs;
    for (int k0 = 0; k0 < K; k0 += 64) {
        #pragma unroll
        for (int it = 0; it < 4; it++) {
            int c = (it * 4 + w) * 64 + lane;   // 0..1023 chunk slots
            int row = c >> 3, phys = c & 7;
            int kc = phys ^ (row & 7);          // XOR swizzle: break 128B-stride bank aliasing
            gload16(A  + (size_t)(m0 + row) * K + k0 + kc * 8, As + (size_t)c * 8);
            gload16(BT + (size_t)(n0 + row) * K + k0 + kc * 8, Bs + (size_t)c * 8);
        }
        __syncthreads();
        #pragma unroll
        for (int ks = 0; ks < 2; ks++) {
            bf16x8 a[4], b[4];
            #pragma unroll
            for (int i = 0; i < 4; i++) {
                int chunk = (ks * 4 + quad) ^ swz;
                a[i] = *(const bf16x8*)&Xs[(wr + i * 16 + l16) * 64 + chunk * 8];
            }
            #pragma unroll
            for (int j = 0; j < 4; j++) {
                int chunk = (ks * 4 + quad) ^ swz;
                b[j] = *(const bf16x8*)&Ys[(wc + j * 16 + l16) * 64 + chunk * 8];
            }
            #pragma unroll
            for (int i = 0; i < 4; i++)
                #pragma unroll
                for (int j = 0; j < 4; j++)
                    acc[i][j] = __builtin_amdgcn_mfma_f32_16x16x32_bf16(a[i], b[j], acc[i][j], 0, 0, 0);
        }
        __syncthreads();
    }

    // ---------- epilogue (bf16, LDS-staged, coalesced 128B rows) ----------
    u16* st = smem + w * 4096;          // per-wave 64x64 bf16 stage (reuses tile LDS)
    #pragma unroll
    for (int i = 0; i < 4; i++) {
        #pragma unroll
        for (int j = 0; j < 4; j++) {
            int gcol = n0 + wc + j * 16 + l16;
            float bc = 0.f;
            if (flags & GF_QKV) { if (!vtb) bc = ((const float*)bias)[gcol]; }
            else if (bias) bc = ldf(bias, gcol, isbf);
            #pragma unroll
            for (int r2 = 0; r2 < 4; r2++) {
                int lrow = wr + i * 16 + quad * 4 + r2;
                int grow = m0 + lrow;
                if (vtb) bc = ((const float*)bias)[n0 + lrow];   // channel-indexed bias
                float v = acc[i][j][r2] + bc;
                if (flags & GF_GELU) v = fast_gelu(v);
                if (flags & GF_RES_BF16) v += bf2f(((const u16*)resv)[(size_t)grow * N + gcol]);
                if (flags & GF_RES_PATCH) {
                    int nn = grow >> 8, s = grow & 255;
                    int iy = ((nn >> 3) << 3) + (s >> 4);
                    int ix = ((nn & 7) << 3) + (s & 15);
                    if (iy < P_DIM && ix < P_DIM)
                        v += ldf(resv, (size_t)(iy * P_DIM + ix) * C_DIM + gcol, isbf);
                }
                st[(i * 16 + quad * 4 + r2) * 64 + j * 16 + l16] = f2bf(v);
            }
        }
    }
    asm volatile("" ::: "memory");   // same-wave LDS: block reorder, no barrier needed
    u16* cdst; int cst;
    if (flags & GF_QKV) {
        if (region == 0) {          // q: compact patch rows, pre-scaled
            cst = 512;
            cdst = (u16*)Cout  + (size_t)(((m0 >> 9) << 8) + (m0 & 255) + wr) * 512 + (n0 + wc);
        } else if (region == 1) {   // k
            cst = 512;
            cdst = (u16*)Cout2 + (size_t)(m0 + wr) * 512 + (n0 - 512 + wc);
        } else {                    // v^T: rows = channels, cols = tokens
            cst = NROW;
            cdst = (u16*)Cout3 + (size_t)(n0 - 1024 + wr) * NROW + (m0 + wc);
        }
    } else {
        cst = ldc;
        cdst = (u16*)Cout + (size_t)(m0 + wr) * ldc + (n0 + wc);
    }
    #pragma unroll
    for (int rr = 0; rr < 8; rr++) {
        int row = rr * 8 + (lane >> 3);
        uint4 val = *(const uint4*)&st[row * 64 + (lane & 7) * 8];
        *(uint4*)(cdst + (size_t)row * cst + (lane & 7) * 8) = val;   // 128B/row coalesced
    }
}

// ---------------- flash attention per (window, head); patch queries only ----------------
__global__ __launch_bounds__(256) void attn_kernel(
    const u16* __restrict__ q, const u16* __restrict__ k, const u16* __restrict__ vtg,
    const unsigned char* __restrict__ validk,
    u16* __restrict__ o)
{
    __shared__ u16 sK[64 * 64];          // [key][d], DMA-staged, swizzled chunks
    __shared__ u16 sV[64 * 64];          // [d][key], DMA-staged from V^T, swizzled chunks
    __shared__ u16 sP[4 * 64 * 64];      // per-wave P tile, chunk-swizzled (48KB total LDS)
    int h = blockIdx.x, n = blockIdx.y;
    int tid = threadIdx.x;
    int w = tid >> 6, lane = tid & 63;
    int l16 = lane & 15, quad = lane >> 4;
    int swz = (l16 & 7);

    bf16x8 qf[4][2];
    #pragma unroll
    for (int i = 0; i < 4; i++)
        #pragma unroll
        for (int ks = 0; ks < 2; ks++) {
            int row = n * A_TOK + w * 64 + i * 16 + l16;       // compact q
            int col = h * HDIM + ks * 32 + quad * 8;
            qf[i][ks] = *(const bf16x8*)(q + (size_t)row * C_DIM + col);
        }

    f32x4 oacc[4][4];
    float lsum[4][4];
    #pragma unroll
    for (int i = 0; i < 4; i++)
        #pragma unroll
        for (int j = 0; j < 4; j++) {
            oacc[i][j][0] = 0.f; oacc[i][j][1] = 0.f; oacc[i][j][2] = 0.f; oacc[i][j][3] = 0.f;
            lsum[i][j] = 0.f;
        }

    for (int ktile = 0; ktile < 8; ktile++) {
        __syncthreads();                       // prior tile's readers done before overwrite
        #pragma unroll
        for (int it = 0; it < 2; it++) {
            int c = it * 256 + w * 64 + lane;  // 0..511 chunk slots
            int row = c >> 3, phys = c & 7;
            int kc = phys ^ (row & 7);
            int grow = n * S_TOK + ktile * 64 + row;
            gload16(k + (size_t)grow * C_DIM + h * HDIM + kc * 8, sK + (size_t)c * 8);
            gload16(vtg + (size_t)(h * HDIM + row) * (size_t)NROW + n * S_TOK + ktile * 64 + kc * 8,
                    sV + (size_t)c * 8);
        }
        __syncthreads();

        f32x4 sacc[4][4];
        #pragma unroll
        for (int i = 0; i < 4; i++)
            #pragma unroll
            for (int j = 0; j < 4; j++) { sacc[i][j][0] = 0.f; sacc[i][j][1] = 0.f; sacc[i][j][2] = 0.f; sacc[i][j][3] = 0.f; }
        #pragma unroll
        for (int ks = 0; ks < 2; ks++) {
            int chunk = (ks * 4 + quad) ^ swz;
            bf16x8 bfr[4];
            #pragma unroll
            for (int j = 0; j < 4; j++) bfr[j] = *(const bf16x8*)&sK[(j * 16 + l16) * 64 + chunk * 8];
            #pragma unroll
            for (int i = 0; i < 4; i++)
                #pragma unroll
                for (int j = 0; j < 4; j++)
                    sacc[i][j] = __builtin_amdgcn_mfma_f32_16x16x32_bf16(qf[i][ks], bfr[j], sacc[i][j], 0, 0, 0);
        }

        bool kvalid[4];
        #pragma unroll
        for (int j = 0; j < 4; j++)
            kvalid[j] = validk[n * S_TOK + ktile * 64 + j * 16 + l16] != 0;

        #pragma unroll
        for (int i = 0; i < 4; i++)
            #pragma unroll
            for (int r2 = 0; r2 < 4; r2++) {
                int prow = i * 16 + quad * 4 + r2;
                #pragma unroll
                for (int j = 0; j < 4; j++) {
                    float p = kvalid[j] ? __expf(sacc[i][j][r2]) : 0.f;
                    lsum[i][r2] += p;
                    int col = j * 16 + l16;
                    int chunk = (col >> 3) ^ (prow & 7);
                    sP[(w * 64 + prow) * 64 + chunk * 8 + (col & 7)] = f2bf(p);
                }
            }
        asm volatile("" ::: "memory");   // per-wave LDS: forbid read-before-write reorder
        #pragma unroll
        for (int ks = 0; ks < 2; ks++) {
            int chunk = (ks * 4 + quad) ^ swz;
            bf16x8 pa[4], vb[4];
            #pragma unroll
            for (int i = 0; i < 4; i++)   pa[i]  = *(const bf16x8*)&sP[(w * 64 + i * 16 + l16) * 64 + chunk * 8];
            #pragma unroll
            for (int jd = 0; jd < 4; jd++) vb[jd] = *(const bf16x8*)&sV[(jd * 16 + l16) * 64 + chunk * 8];
            #pragma unroll
            for (int i = 0; i < 4; i++)
                #pragma unroll
                for (int jd = 0; jd < 4; jd++)
                    oacc[i][jd] = __builtin_amdgcn_mfma_f32_16x16x32_bf16(pa[i], vb[jd], oacc[i][jd], 0, 0, 0);
        }
    }

    // normalize, stage O per-wave in LDS, coalesced 128B stores
    asm volatile("" ::: "memory");
    u16* ost = sP + w * 4096;            // flat 64x64 region, stride 64 (sP data dead)
    #pragma unroll
    for (int i = 0; i < 4; i++) {
        #pragma unroll
        for (int r2 = 0; r2 < 4; r2++) {
            float l = lsum[i][r2];
            #pragma unroll
            for (int off = 8; off; off >>= 1)
                l += __shfl_xor(l, off, 64);
            float inv = (l > 0.f) ? 1.f / l : 0.f;
            #pragma unroll
            for (int jd = 0; jd < 4; jd++)
                ost[(i * 16 + quad * 4 + r2) * 64 + jd * 16 + l16] = f2bf(oacc[i][jd][r2] * inv);
        }
    }
    asm volatile("" ::: "memory");
    u16* obase = o + (size_t)(n * A_TOK + w * 64) * C_DIM + h * HDIM;
    #pragma unroll
    for (int rr = 0; rr < 8; rr++) {
        int row = rr * 8 + (lane >> 3);
        uint4 val = *(const uint4*)&ost[row * 64 + (lane & 7) * 8];
        *(uint4*)(obase + (size_t)row * C_DIM + (lane & 7) * 8) = val;
    }
}

// ---------------- final gather-average (bf16 input) ----------------
__global__ __launch_bounds__(256) void gather_kernel(const u16* __restrict__ xf,
                                                     void* __restrict__ out,
                                                     const int* __restrict__ flagp)
{
    int isbf = *flagp;
    int gid = blockIdx.x * 256 + threadIdx.x;    // pixel*128 + 4-elem chunk
    int p = gid >> 7, cv = gid & 127;
    int py = p >> 6, px = p & 63;
    float4 acc = make_float4(0.f, 0.f, 0.f, 0.f);
    int cnt = 0;
    #pragma unroll
    for (int dy = 0; dy < 2; dy++) {
        int y0 = ((py >> 3) - dy) << 3;
        if (y0 < 0) continue;
        #pragma unroll
        for (int dx = 0; dx < 2; dx++) {
            int x0 = ((px >> 3) - dx) << 3;
            if (x0 < 0) continue;
            int n = ((y0 >> 3) << 3) + (x0 >> 3);
            int s = (py - y0) * 16 + (px - x0);
            float4 t = bf4f(((const ushort4*)(xf + (size_t)(n * A_TOK + s) * C_DIM))[cv]);
            acc.x += t.x; acc.y += t.y; acc.z += t.z; acc.w += t.w;
            cnt++;
        }
    }
    float inv = 1.f / (float)cnt;
    acc.x *= inv; acc.y *= inv; acc.z *= inv; acc.w *= inv;
    if (isbf) {
        ushort4 o;
        o.x = f2bf(acc.x); o.y = f2bf(acc.y); o.z = f2bf(acc.z); o.w = f2bf(acc.w);
        ((ushort4*)out)[gid] = o;
    } else {
        ((float4*)out)[gid] = acc;
    }
}

extern "C" void kernel_launch(void* const* d_in, const int* in_sizes, int n_in,
                              void* d_out, int out_size, void* d_ws, size_t ws_size,
                              hipStream_t stream)
{
    const void* patch = d_in[0];
    const void* vox   = d_in[1];
    const void* ln1g  = d_in[2];
    const void* ln1b  = d_in[3];
    const void* wq = d_in[4];  const void* bq = d_in[5];
    const void* wk = d_in[6];  const void* bk = d_in[7];
    const void* wv = d_in[8];  const void* bv = d_in[9];
    const void* wo = d_in[10]; const void* bo = d_in[11];
    const void* ln2g = d_in[12];
    const void* ln2b = d_in[13];
    const void* w1 = d_in[14]; const void* b1 = d_in[15];
    const void* w2 = d_in[16]; const void* b2 = d_in[17];
    const int* vpy = (const int*)d_in[18];
    const int* vpx = (const int*)d_in[19];

    const size_t MB = 1ull << 20;
    char* ws = (char*)d_ws;
    if (ws_size < 183 * MB) return;   // insufficient workspace -> visible failure

    u16*  hbuf  = (u16*)(ws + 0);          // [32768][512] bf16, 32MB
    u16*  kbuf  = (u16*)(ws + 32 * MB);    // [32768][512] bf16, 32MB
    u16*  vtt   = (u16*)(ws + 64 * MB);    // V^T [512][32768] bf16, 32MB
    u16*  qbuf  = (u16*)(ws + 96 * MB);    // [16384][512] bf16, 16MB (compact patch)
    u16*  obuf  = (u16*)(ws + 112 * MB);   // 16MB
    u16*  xbuf16 = (u16*)(ws + 128 * MB);  // x residual [16384][512] bf16, 16MB
    u16*  h2buf = (u16*)(ws + 160 * MB);   // 16MB
    u16*  tbuf  = (u16*)(ws + 0);          // [16384][2048] bf16, 64MB (reuse h+k, dead)
    u16*  xfbuf = (u16*)(ws + 64 * MB);    // [16384][512] bf16, 16MB (reuse vtt, dead)
    u16* wqkvT = (u16*)(ws + 176 * MB);    // [1536][512] bf16, 1.5MB (q rows pre-scaled)
    u16* woT  = (u16*)(ws + 177 * MB + 512 * 1024);
    u16* w1T  = (u16*)(ws + 178 * MB);     // [2048][512], 2MB
    u16* w2T  = (u16*)(ws + 180 * MB);     // [512][2048], 2MB
    int* sel = (int*)(ws + 182 * MB);      // 64KB
    unsigned char* validk = (unsigned char*)(ws + 182 * MB + 64 * 1024); // 32KB
    int* flagp = (int*)(ws + 182 * MB + 128 * 1024);
    float* bqkv = (float*)(ws + 182 * MB + 132 * 1024);  // [1536] f32

    detect_kernel<<<1, 256, 0, stream>>>((const u32*)patch, flagp);

    wtrans_all_kernel<<<3072, dim3(32, 8), 0, stream>>>(wq, wk, wv, wo, w1, w2,
        wqkvT, woT, w1T, w2T, flagp);
    prep_bias_kernel<<<6, 256, 0, stream>>>(bq, bk, bv, flagp, bqkv);

    voxsel_kernel<<<NWIN, 64, 0, stream>>>(vpy, vpx, sel);
    ln1_kernel<<<NROW / 4, 256, 0, stream>>>(patch, vox, ln1g, ln1b, sel, flagp, hbuf, validk);

    // fused QKV gemm: one tile/block, XCD-local remap inside kernel
    gemm_kernel<<<dim3(12, NROW / 128), 256, 0, stream>>>(hbuf, wqkvT, bqkv,
        qbuf, kbuf, vtt, nullptr, flagp, NROW, 1536, 512, GF_QKV, 512);

    attn_kernel<<<dim3(HEADS, NWIN), 256, 0, stream>>>(qbuf, kbuf, vtt, validk, obuf);

    // x = tokens(patch gather) + o @ wo + bo   (bf16, coalesced staged store)
    gemm_kernel<<<dim3(4, NPATCH / 128), 256, 0, stream>>>(obuf, woT, bo,
        xbuf16, nullptr, nullptr, patch, flagp, NPATCH, 512, 512, GF_RES_PATCH, 512);

    ln2_kernel<<<NPATCH / 4, 256, 0, stream>>>(xbuf16, ln2g, ln2b, flagp, h2buf);

    gemm_kernel<<<dim3(16, NPATCH / 128), 256, 0, stream>>>(h2buf, w1T, b1,
        tbuf, nullptr, nullptr, nullptr, flagp, NPATCH, 2048, 512, GF_GELU, 2048);
    gemm_kernel<<<dim3(4, NPATCH / 128), 256, 0, stream>>>(tbuf, w2T, b2,
        xfbuf, nullptr, nullptr, xbuf16, flagp, NPATCH, 512, 2048, GF_RES_BF16, 512);

    gather_kernel<<<(4096 * 128) / 256, 256, 0, stream>>>(xfbuf, d_out, flagp);
}

// Round 9
// 442.090 us; speedup vs baseline: 1.5993x; 1.0095x over previous
//
#include <hip/hip_runtime.h>
#include <math.h>

using u16 = unsigned short;
using u32 = unsigned int;
using u64 = unsigned long long;
using bf16x8 = __attribute__((ext_vector_type(8))) short;
using f32x4  = __attribute__((ext_vector_type(4))) float;

#define C_DIM   512
#define HEADS   8
#define HDIM    64
#define P_DIM   64
#define A_TOK   256
#define VCAP    256
#define S_TOK   512
#define NWIN    64
#define NROW    32768      // NWIN * S_TOK
#define NPATCH  16384      // NWIN * A_TOK
#define MLP_DIM 2048
#define NV_TOT  2048

__device__ __forceinline__ float bf2f(u16 b) { return __uint_as_float(((u32)b) << 16); }
__device__ __forceinline__ u16 f2bf(float f) {
    u32 u = __float_as_uint(f);
    return (u16)((u + 0x7fffu + ((u >> 16) & 1u)) >> 16);   // RNE
}
__device__ __forceinline__ float4 bf4f(ushort4 v) {
    return make_float4(bf2f(v.x), bf2f(v.y), bf2f(v.z), bf2f(v.w));
}
// dtype-agnostic loads from RAW inputs: isbf=1 -> bf16, else f32
__device__ __forceinline__ float ldf(const void* p, size_t e, int isbf) {
    return isbf ? bf2f(((const u16*)p)[e]) : ((const float*)p)[e];
}
__device__ __forceinline__ float4 ld4(const void* p, size_t e, int isbf) {  // e % 4 == 0
    if (isbf) return bf4f(*(const ushort4*)((const u16*)p + e));
    return *(const float4*)((const float*)p + e);
}
// async global->LDS, 16B per lane; lds dest must be wave-uniform-base + lane*16
__device__ __forceinline__ void gload16(const u16* g, u16* l) {
    __builtin_amdgcn_global_load_lds(
        (const __attribute__((address_space(1))) u32*)g,
        (__attribute__((address_space(3))) u32*)l, 16, 0, 0);
}
// tanh-form GELU via sigmoid: x*sigmoid(1.5957691x + 0.0713548x^3); |err| <= ~3e-4
__device__ __forceinline__ float fast_gelu(float x) {
    float x2 = x * x;
    float z = x * (-1.5957691216f - 0.07135481283f * x2);
    return x / (1.f + __expf(z));
}

// ---------------- dtype detector: vote on low-16-bits-as-bf16 plausibility ----------------
__global__ void detect_kernel(const u32* __restrict__ patch, int* __restrict__ flag)
{
    __shared__ int sm[256];
    int t = threadIdx.x;
    int cnt = 0;
    for (int i = t; i < 4096; i += 256) {
        u32 w = patch[i];
        float v = __uint_as_float((w & 0xffffu) << 16);
        float a = fabsf(v);
        if (a > 1e-8f && a < 1e4f) cnt++;
    }
    sm[t] = cnt;
    __syncthreads();
    for (int o = 128; o; o >>= 1) { if (t < o) sm[t] += sm[t + o]; __syncthreads(); }
    if (t == 0) *flag = (sm[0] > 2458) ? 1 : 0;    // >60% plausible => bf16 world
}

// ------------- merged weight transposes: all six [K][N] -> [N][K] bf16 in one dispatch -------------
__global__ void wtrans_all_kernel(const void* __restrict__ wq, const void* __restrict__ wk,
                                  const void* __restrict__ wv, const void* __restrict__ wo,
                                  const void* __restrict__ w1, const void* __restrict__ w2,
                                  u16* __restrict__ wqkvT, u16* __restrict__ woT,
                                  u16* __restrict__ w1T, u16* __restrict__ w2T,
                                  const int* __restrict__ flagp)
{
    __shared__ u16 tile[32][33];
    int isbf = *flagp;
    int id = blockIdx.x;
    const void* in; u16* out; int K, N; float sc = 1.f;
    if (id < 256)       { in = wq; out = wqkvT;              K = 512;  N = 512;  sc = 0.125f; }
    else if (id < 512)  { id -= 256;  in = wk; out = wqkvT + 512 * 512;  K = 512;  N = 512; }
    else if (id < 768)  { id -= 512;  in = wv; out = wqkvT + 1024 * 512; K = 512;  N = 512; }
    else if (id < 1024) { id -= 768;  in = wo; out = woT;    K = 512;  N = 512; }
    else if (id < 2048) { id -= 1024; in = w1; out = w1T;    K = 512;  N = 2048; }
    else                { id -= 2048; in = w2; out = w2T;    K = 2048; N = 512; }
    int ntx = N >> 5;
    int n0 = (id % ntx) * 32, k0 = (id / ntx) * 32;
    int tx = threadIdx.x, ty = threadIdx.y;   // block (32, 8)
    #pragma unroll
    for (int i = 0; i < 4; i++)
        tile[ty + i * 8][tx] = f2bf(sc * ldf(in, (size_t)(k0 + ty + i * 8) * N + (n0 + tx), isbf));
    __syncthreads();
    #pragma unroll
    for (int i = 0; i < 4; i++)
        out[(size_t)(n0 + ty + i * 8) * K + (k0 + tx)] = tile[tx][ty + i * 8];
}

// ---------------- fused q/k/v bias vector (q part pre-scaled), f32 ----------------
__global__ void prep_bias_kernel(const void* __restrict__ bq, const void* __restrict__ bk,
                                 const void* __restrict__ bv,
                                 const int* __restrict__ flagp, float* __restrict__ bqkv)
{
    int isbf = *flagp;
    int t = blockIdx.x * 256 + threadIdx.x;
    if (t < 512)       bqkv[t] = 0.125f * ldf(bq, t, isbf);
    else if (t < 1024) bqkv[t] = ldf(bk, t - 512, isbf);
    else if (t < 1536) bqkv[t] = ldf(bv, t - 1024, isbf);
}

// ---------------- per-window voxel selection (stable order, cap 256) + counts ----------------
__global__ void voxsel_kernel(const int* __restrict__ vy, const int* __restrict__ vx,
                              int* __restrict__ sel, int* __restrict__ wcnt)
{
    int n = blockIdx.x;                 // 64 windows, 64 threads (1 wave)
    int lane = threadIdx.x;
    int y0 = (n >> 3) << 3, x0 = (n & 7) << 3;
    int count = 0;
    for (int base = 0; base < NV_TOT; base += 64) {
        int v = base + lane;
        int yy = vy[v], xx = vx[v];
        bool m = (yy >= y0) && (yy < y0 + 16) && (xx >= x0) && (xx < x0 + 16);
        u64 mask = __ballot(m);
        int pos = count + __popcll(mask & ((1ull << lane) - 1ull));
        if (m && pos < VCAP) sel[n * VCAP + pos] = v;
        count += __popcll(mask);
    }
    for (int j = lane; j < VCAP; j += 64)
        if (j >= count) sel[n * VCAP + j] = -1;
    if (lane == 0) wcnt[n] = count < VCAP ? count : VCAP;
}

// ---------------- gather tokens + LN1 -> h (bf16), validity flags ----------------
__global__ __launch_bounds__(256) void ln1_kernel(
    const void* __restrict__ patch, const void* __restrict__ vox,
    const void* __restrict__ g, const void* __restrict__ b,
    const int* __restrict__ sel, const int* __restrict__ flagp,
    u16* __restrict__ h, unsigned char* __restrict__ validk)
{
    int isbf = *flagp;
    int r = blockIdx.x * 4 + (threadIdx.x >> 6);    // one wave per row
    int lane = threadIdx.x & 63;
    int n = r >> 9, s = r & 511;
    const void* tok = nullptr;
    size_t base = 0;
    bool valid;
    if (s < A_TOK) {
        int wy = s >> 4, wx = s & 15;
        int iy = ((n >> 3) << 3) + wy, ix = ((n & 7) << 3) + wx;
        valid = (iy < P_DIM) && (ix < P_DIM);
        tok = patch; base = (size_t)(iy * P_DIM + ix) * C_DIM;
    } else {
        int idx = sel[n * VCAP + (s - A_TOK)];
        valid = (idx >= 0);
        tok = vox; base = valid ? (size_t)idx * C_DIM : 0;
    }
    float4 xa = make_float4(0.f, 0.f, 0.f, 0.f), xb = xa;
    if (valid) {
        xa = ld4(tok, base + lane * 4, isbf);
        xb = ld4(tok, base + 256 + lane * 4, isbf);
    }
    float sum = xa.x + xa.y + xa.z + xa.w + xb.x + xb.y + xb.z + xb.w;
    float sq  = xa.x * xa.x + xa.y * xa.y + xa.z * xa.z + xa.w * xa.w
              + xb.x * xb.x + xb.y * xb.y + xb.z * xb.z + xb.w * xb.w;
    #pragma unroll
    for (int off = 32; off; off >>= 1) {
        sum += __shfl_xor(sum, off, 64);
        sq  += __shfl_xor(sq,  off, 64);
    }
    float mean = sum * (1.f / C_DIM);
    float var  = fmaxf(sq * (1.f / C_DIM) - mean * mean, 0.f);
    float rstd = rsqrtf(var + 1e-5f);
    float4 ga = ld4(g, lane * 4, isbf);
    float4 gb = ld4(g, 256 + lane * 4, isbf);
    float4 ba = ld4(b, lane * 4, isbf);
    float4 bb = ld4(b, 256 + lane * 4, isbf);
    ushort4 oa, ob;
    oa.x = f2bf((xa.x - mean) * rstd * ga.x + ba.x);
    oa.y = f2bf((xa.y - mean) * rstd * ga.y + ba.y);
    oa.z = f2bf((xa.z - mean) * rstd * ga.z + ba.z);
    oa.w = f2bf((xa.w - mean) * rstd * ga.w + ba.w);
    ob.x = f2bf((xb.x - mean) * rstd * gb.x + bb.x);
    ob.y = f2bf((xb.y - mean) * rstd * gb.y + bb.y);
    ob.z = f2bf((xb.z - mean) * rstd * gb.z + bb.z);
    ob.w = f2bf((xb.w - mean) * rstd * gb.w + bb.w);
    ((ushort4*)(h + (size_t)r * C_DIM))[lane]      = oa;
    ((ushort4*)(h + (size_t)r * C_DIM))[lane + 64] = ob;
    if (lane == 0) validk[r] = valid ? 1 : 0;
}

// ---------------- LN2 over bf16 rows -> bf16 ----------------
__global__ __launch_bounds__(256) void ln2_kernel(
    const u16* __restrict__ x,
    const void* __restrict__ g, const void* __restrict__ b,
    const int* __restrict__ flagp,
    u16* __restrict__ h2)
{
    int isbf = *flagp;
    int r = blockIdx.x * 4 + (threadIdx.x >> 6);
    int lane = threadIdx.x & 63;
    const u16* src = x + (size_t)r * C_DIM;
    float4 xa = bf4f(((const ushort4*)src)[lane]);
    float4 xb = bf4f(((const ushort4*)src)[lane + 64]);
    float sum = xa.x + xa.y + xa.z + xa.w + xb.x + xb.y + xb.z + xb.w;
    float sq  = xa.x * xa.x + xa.y * xa.y + xa.z * xa.z + xa.w * xa.w
              + xb.x * xb.x + xb.y * xb.y + xb.z * xb.z + xb.w * xb.w;
    #pragma unroll
    for (int off = 32; off; off >>= 1) {
        sum += __shfl_xor(sum, off, 64);
        sq  += __shfl_xor(sq,  off, 64);
    }
    float mean = sum * (1.f / C_DIM);
    float var  = fmaxf(sq * (1.f / C_DIM) - mean * mean, 0.f);
    float rstd = rsqrtf(var + 1e-5f);
    float4 ga = ld4(g, lane * 4, isbf);
    float4 gb = ld4(g, 256 + lane * 4, isbf);
    float4 ba = ld4(b, lane * 4, isbf);
    float4 bb = ld4(b, 256 + lane * 4, isbf);
    ushort4 oa, ob;
    oa.x = f2bf((xa.x - mean) * rstd * ga.x + ba.x);
    oa.y = f2bf((xa.y - mean) * rstd * ga.y + ba.y);
    oa.z = f2bf((xa.z - mean) * rstd * ga.z + ba.z);
    oa.w = f2bf((xa.w - mean) * rstd * ga.w + ba.w);
    ob.x = f2bf((xb.x - mean) * rstd * gb.x + bb.x);
    ob.y = f2bf((xb.y - mean) * rstd * gb.y + bb.y);
    ob.z = f2bf((xb.z - mean) * rstd * gb.z + bb.z);
    ob.w = f2bf((xb.w - mean) * rstd * gb.w + bb.w);
    ((ushort4*)(h2 + (size_t)r * C_DIM))[lane]      = oa;
    ((ushort4*)(h2 + (size_t)r * C_DIM))[lane + 64] = ob;
}

// ---------------- generic bf16 MFMA GEMM: C = op(A @ B^T + bias), one tile/block ----------------
// XCD-local block remap for ALL dispatches (gridDim.y % 8 == 0): all gridDim.x n-tiles of an
// m-tile run adjacently on one XCD (xcd = linear_id % 8 heuristic) -> A-tile hits one L2.
#define GF_GELU      2
#define GF_RES_BF16  8    // += res (bf16, [M][N])
#define GF_RES_PATCH 16   // += gathered patch token (raw dtype), valid positions only
#define GF_QKV       32   // N=1536: cols 0-511 q (compact, patch rows), 512-1023 k, 1024-1535 v^T

__global__ __launch_bounds__(256) void gemm_kernel(
    const u16* __restrict__ A, const u16* __restrict__ BT,
    const void* __restrict__ bias,
    void* __restrict__ Cout, void* __restrict__ Cout2, void* __restrict__ Cout3,
    const void* __restrict__ resv,
    const int* __restrict__ flagp, const int* __restrict__ wcnt,
    int M, int N, int K, int flags, int ldc)
{
    __shared__ u16 smem[2 * 128 * 64];   // As = smem, Bs = smem+8192 (u16); epilogue stage reuse
    int tid = threadIdx.x;
    int nt, mt;
    int gx = gridDim.x, gy = gridDim.y;
    if ((gy & 7) == 0) {
        // XCD-local remap: linear id L (x fastest), xcd = L % 8 (round-robin heuristic).
        int L = blockIdx.x + gx * blockIdx.y;
        int c = L & 7, s = L >> 3;
        mt = c * (gy >> 3) + s / gx;
        nt = s % gx;
    } else { nt = blockIdx.x; mt = blockIdx.y; }
    int m0 = mt << 7, n0 = nt << 7;
    int region = (flags & GF_QKV) ? (nt >> 2) : 0;   // 0:q 1:k 2:v^T
    if (flags & GF_QKV) {
        int lo = m0 & 511;
        if (region == 0 && lo >= 256) return;        // voxel rows need no Q
        // empty voxel-slot tiles need no K/V (poison stays; attention masks/skips them)
        if (region >= 1 && lo >= 256 && wcnt[m0 >> 9] <= lo - 256) return;
    }
    int isbf = *flagp;
    int w = tid >> 6, lane = tid & 63;
    int wr = (w >> 1) * 64, wc = (w & 1) * 64;
    int l16 = lane & 15, quad = lane >> 4;
    u16* As = smem;
    u16* Bs = smem + 8192;
    bool vtb = (flags & GF_QKV) && (region == 2);   // transposed-output block

    f32x4 acc[4][4];
    #pragma unroll
    for (int i = 0; i < 4; i++)
        #pragma unroll
        for (int j = 0; j < 4; j++) { acc[i][j][0] = 0.f; acc[i][j][1] = 0.f; acc[i][j][2] = 0.f; acc[i][j][3] = 0.f; }

    int swz = (l16 & 7);                   // frag-read chunk swizzle key
    const u16* Xs = vtb ? Bs : As;         // first operand rows -> D rows
    const u16* Ys = vtb ? As : Bs;
    for (int k0 = 0; k0 < K; k0 += 64) {
        #pragma unroll
        for (int it = 0; it < 4; it++) {
            int c = (it * 4 + w) * 64 + lane;   // 0..1023 chunk slots
            int row = c >> 3, phys = c & 7;
            int kc = phys ^ (row & 7);          // XOR swizzle: break 128B-stride bank aliasing
            gload16(A  + (size_t)(m0 + row) * K + k0 + kc * 8, As + (size_t)c * 8);
            gload16(BT + (size_t)(n0 + row) * K + k0 + kc * 8, Bs + (size_t)c * 8);
        }
        __syncthreads();
        #pragma unroll
        for (int ks = 0; ks < 2; ks++) {
            bf16x8 a[4], b[4];
            #pragma unroll
            for (int i = 0; i < 4; i++) {
                int chunk = (ks * 4 + quad) ^ swz;
                a[i] = *(const bf16x8*)&Xs[(wr + i * 16 + l16) * 64 + chunk * 8];
            }
            #pragma unroll
            for (int j = 0; j < 4; j++) {
                int chunk = (ks * 4 + quad) ^ swz;
                b[j] = *(const bf16x8*)&Ys[(wc + j * 16 + l16) * 64 + chunk * 8];
            }
            #pragma unroll
            for (int i = 0; i < 4; i++)
                #pragma unroll
                for (int j = 0; j < 4; j++)
                    acc[i][j] = __builtin_amdgcn_mfma_f32_16x16x32_bf16(a[i], b[j], acc[i][j], 0, 0, 0);
        }
        __syncthreads();
    }

    // ---------- epilogue (bf16, LDS-staged, coalesced 128B rows) ----------
    u16* st = smem + w * 4096;          // per-wave 64x64 bf16 stage (reuses tile LDS)
    #pragma unroll
    for (int i = 0; i < 4; i++) {
        #pragma unroll
        for (int j = 0; j < 4; j++) {
            int gcol = n0 + wc + j * 16 + l16;
            float bc = 0.f;
            if (flags & GF_QKV) { if (!vtb) bc = ((const float*)bias)[gcol]; }
            else if (bias) bc = ldf(bias, gcol, isbf);
            #pragma unroll
            for (int r2 = 0; r2 < 4; r2++) {
                int lrow = wr + i * 16 + quad * 4 + r2;
                int grow = m0 + lrow;
                if (vtb) bc = ((const float*)bias)[n0 + lrow];   // channel-indexed bias
                float v = acc[i][j][r2] + bc;
                if (flags & GF_GELU) v = fast_gelu(v);
                if (flags & GF_RES_BF16) v += bf2f(((const u16*)resv)[(size_t)grow * N + gcol]);
                if (flags & GF_RES_PATCH) {
                    int nn = grow >> 8, s = grow & 255;
                    int iy = ((nn >> 3) << 3) + (s >> 4);
                    int ix = ((nn & 7) << 3) + (s & 15);
                    if (iy < P_DIM && ix < P_DIM)
                        v += ldf(resv, (size_t)(iy * P_DIM + ix) * C_DIM + gcol, isbf);
                }
                st[(i * 16 + quad * 4 + r2) * 64 + j * 16 + l16] = f2bf(v);
            }
        }
    }
    asm volatile("" ::: "memory");   // same-wave LDS: block reorder, no barrier needed
    u16* cdst; int cst;
    if (flags & GF_QKV) {
        if (region == 0) {          // q: compact patch rows, pre-scaled
            cst = 512;
            cdst = (u16*)Cout  + (size_t)(((m0 >> 9) << 8) + (m0 & 255) + wr) * 512 + (n0 + wc);
        } else if (region == 1) {   // k
            cst = 512;
            cdst = (u16*)Cout2 + (size_t)(m0 + wr) * 512 + (n0 - 512 + wc);
        } else {                    // v^T: rows = channels, cols = tokens
            cst = NROW;
            cdst = (u16*)Cout3 + (size_t)(n0 - 1024 + wr) * NROW + (m0 + wc);
        }
    } else {
        cst = ldc;
        cdst = (u16*)Cout + (size_t)(m0 + wr) * ldc + (n0 + wc);
    }
    #pragma unroll
    for (int rr = 0; rr < 8; rr++) {
        int row = rr * 8 + (lane >> 3);
        uint4 val = *(const uint4*)&st[row * 64 + (lane & 7) * 8];
        *(uint4*)(cdst + (size_t)row * cst + (lane & 7) * 8) = val;   // 128B/row coalesced
    }
}

// ---------------- flash attention per (window, head); patch queries only ----------------
__global__ __launch_bounds__(256) void attn_kernel(
    const u16* __restrict__ q, const u16* __restrict__ k, const u16* __restrict__ vtg,
    const unsigned char* __restrict__ validk, const int* __restrict__ wcnt,
    u16* __restrict__ o)
{
    __shared__ u16 sK[64 * 64];          // [key][d], DMA-staged, swizzled chunks
    __shared__ u16 sV[64 * 64];          // [d][key], DMA-staged from V^T, swizzled chunks
    __shared__ u16 sP[4 * 64 * 64];      // per-wave P tile, chunk-swizzled (48KB total LDS)
    int h = blockIdx.x, n = blockIdx.y;
    int tid = threadIdx.x;
    int w = tid >> 6, lane = tid & 63;
    int l16 = lane & 15, quad = lane >> 4;
    int swz = (l16 & 7);
    int cnt = wcnt[n];                   // valid voxel slots in this window

    bf16x8 qf[4][2];
    #pragma unroll
    for (int i = 0; i < 4; i++)
        #pragma unroll
        for (int ks = 0; ks < 2; ks++) {
            int row = n * A_TOK + w * 64 + i * 16 + l16;       // compact q
            int col = h * HDIM + ks * 32 + quad * 8;
            qf[i][ks] = *(const bf16x8*)(q + (size_t)row * C_DIM + col);
        }

    f32x4 oacc[4][4];
    float lsum[4][4];
    #pragma unroll
    for (int i = 0; i < 4; i++)
        #pragma unroll
        for (int j = 0; j < 4; j++) {
            oacc[i][j][0] = 0.f; oacc[i][j][1] = 0.f; oacc[i][j][2] = 0.f; oacc[i][j][3] = 0.f;
            lsum[i][j] = 0.f;
        }

    for (int ktile = 0; ktile < 8; ktile++) {
        // voxel key-tiles past the valid count are entirely masked -> skip (block-uniform, monotone)
        if (ktile >= 4 && cnt <= (ktile - 4) * 64) break;
        __syncthreads();                       // prior tile's readers done before overwrite
        #pragma unroll
        for (int it = 0; it < 2; it++) {
            int c = it * 256 + w * 64 + lane;  // 0..511 chunk slots
            int row = c >> 3, phys = c & 7;
            int kc = phys ^ (row & 7);
            int grow = n * S_TOK + ktile * 64 + row;
            gload16(k + (size_t)grow * C_DIM + h * HDIM + kc * 8, sK + (size_t)c * 8);
            gload16(vtg + (size_t)(h * HDIM + row) * (size_t)NROW + n * S_TOK + ktile * 64 + kc * 8,
                    sV + (size_t)c * 8);
        }
        __syncthreads();

        f32x4 sacc[4][4];
        #pragma unroll
        for (int i = 0; i < 4; i++)
            #pragma unroll
            for (int j = 0; j < 4; j++) { sacc[i][j][0] = 0.f; sacc[i][j][1] = 0.f; sacc[i][j][2] = 0.f; sacc[i][j][3] = 0.f; }
        #pragma unroll
        for (int ks = 0; ks < 2; ks++) {
            int chunk = (ks * 4 + quad) ^ swz;
            bf16x8 bfr[4];
            #pragma unroll
            for (int j = 0; j < 4; j++) bfr[j] = *(const bf16x8*)&sK[(j * 16 + l16) * 64 + chunk * 8];
            #pragma unroll
            for (int i = 0; i < 4; i++)
                #pragma unroll
                for (int j = 0; j < 4; j++)
                    sacc[i][j] = __builtin_amdgcn_mfma_f32_16x16x32_bf16(qf[i][ks], bfr[j], sacc[i][j], 0, 0, 0);
        }

        bool kvalid[4];
        #pragma unroll
        for (int j = 0; j < 4; j++)
            kvalid[j] = validk[n * S_TOK + ktile * 64 + j * 16 + l16] != 0;

        #pragma unroll
        for (int i = 0; i < 4; i++)
            #pragma unroll
            for (int r2 = 0; r2 < 4; r2++) {
                int prow = i * 16 + quad * 4 + r2;
                #pragma unroll
                for (int j = 0; j < 4; j++) {
                    float p = kvalid[j] ? __expf(sacc[i][j][r2]) : 0.f;
                    lsum[i][r2] += p;
                    int col = j * 16 + l16;
                    int chunk = (col >> 3) ^ (prow & 7);
                    sP[(w * 64 + prow) * 64 + chunk * 8 + (col & 7)] = f2bf(p);
                }
            }
        asm volatile("" ::: "memory");   // per-wave LDS: forbid read-before-write reorder
        #pragma unroll
        for (int ks = 0; ks < 2; ks++) {
            int chunk = (ks * 4 + quad) ^ swz;
            bf16x8 pa[4], vb[4];
            #pragma unroll
            for (int i = 0; i < 4; i++)   pa[i]  = *(const bf16x8*)&sP[(w * 64 + i * 16 + l16) * 64 + chunk * 8];
            #pragma unroll
            for (int jd = 0; jd < 4; jd++) vb[jd] = *(const bf16x8*)&sV[(jd * 16 + l16) * 64 + chunk * 8];
            #pragma unroll
            for (int i = 0; i < 4; i++)
                #pragma unroll
                for (int jd = 0; jd < 4; jd++)
                    oacc[i][jd] = __builtin_amdgcn_mfma_f32_16x16x32_bf16(pa[i], vb[jd], oacc[i][jd], 0, 0, 0);
        }
    }

    // normalize, stage O per-wave in LDS, coalesced 128B stores
    asm volatile("" ::: "memory");
    __syncthreads();                     // all waves done with sP/sV before O staging reuse
    u16* ost = sP + w * 4096;            // flat 64x64 region, stride 64 (sP data dead)
    #pragma unroll
    for (int i = 0; i < 4; i++) {
        #pragma unroll
        for (int r2 = 0; r2 < 4; r2++) {
            float l = lsum[i][r2];
            #pragma unroll
            for (int off = 8; off; off >>= 1)
                l += __shfl_xor(l, off, 64);
            float inv = (l > 0.f) ? 1.f / l : 0.f;
            #pragma unroll
            for (int jd = 0; jd < 4; jd++)
                ost[(i * 16 + quad * 4 + r2) * 64 + jd * 16 + l16] = f2bf(oacc[i][jd][r2] * inv);
        }
    }
    asm volatile("" ::: "memory");
    u16* obase = o + (size_t)(n * A_TOK + w * 64) * C_DIM + h * HDIM;
    #pragma unroll
    for (int rr = 0; rr < 8; rr++) {
        int row = rr * 8 + (lane >> 3);
        uint4 val = *(const uint4*)&ost[row * 64 + (lane & 7) * 8];
        *(uint4*)(obase + (size_t)row * C_DIM + (lane & 7) * 8) = val;
    }
}

// ---------------- final gather-average (bf16 input) ----------------
__global__ __launch_bounds__(256) void gather_kernel(const u16* __restrict__ xf,
                                                     void* __restrict__ out,
                                                     const int* __restrict__ flagp)
{
    int isbf = *flagp;
    int gid = blockIdx.x * 256 + threadIdx.x;    // pixel*128 + 4-elem chunk
    int p = gid >> 7, cv = gid & 127;
    int py = p >> 6, px = p & 63;
    float4 acc = make_float4(0.f, 0.f, 0.f, 0.f);
    int cnt = 0;
    #pragma unroll
    for (int dy = 0; dy < 2; dy++) {
        int y0 = ((py >> 3) - dy) << 3;
        if (y0 < 0) continue;
        #pragma unroll
        for (int dx = 0; dx < 2; dx++) {
            int x0 = ((px >> 3) - dx) << 3;
            if (x0 < 0) continue;
            int n = ((y0 >> 3) << 3) + (x0 >> 3);
            int s = (py - y0) * 16 + (px - x0);
            float4 t = bf4f(((const ushort4*)(xf + (size_t)(n * A_TOK + s) * C_DIM))[cv]);
            acc.x += t.x; acc.y += t.y; acc.z += t.z; acc.w += t.w;
            cnt++;
        }
    }
    float inv = 1.f / (float)cnt;
    acc.x *= inv; acc.y *= inv; acc.z *= inv; acc.w *= inv;
    if (isbf) {
        ushort4 o;
        o.x = f2bf(acc.x); o.y = f2bf(acc.y); o.z = f2bf(acc.z); o.w = f2bf(acc.w);
        ((ushort4*)out)[gid] = o;
    } else {
        ((float4*)out)[gid] = acc;
    }
}

extern "C" void kernel_launch(void* const* d_in, const int* in_sizes, int n_in,
                              void* d_out, int out_size, void* d_ws, size_t ws_size,
                              hipStream_t stream)
{
    const void* patch = d_in[0];
    const void* vox   = d_in[1];
    const void* ln1g  = d_in[2];
    const void* ln1b  = d_in[3];
    const void* wq = d_in[4];  const void* bq = d_in[5];
    const void* wk = d_in[6];  const void* bk = d_in[7];
    const void* wv = d_in[8];  const void* bv = d_in[9];
    const void* wo = d_in[10]; const void* bo = d_in[11];
    const void* ln2g = d_in[12];
    const void* ln2b = d_in[13];
    const void* w1 = d_in[14]; const void* b1 = d_in[15];
    const void* w2 = d_in[16]; const void* b2 = d_in[17];
    const int* vpy = (const int*)d_in[18];
    const int* vpx = (const int*)d_in[19];

    const size_t MB = 1ull << 20;
    char* ws = (char*)d_ws;
    if (ws_size < 183 * MB) return;   // insufficient workspace -> visible failure

    u16*  hbuf  = (u16*)(ws + 0);          // [32768][512] bf16, 32MB
    u16*  kbuf  = (u16*)(ws + 32 * MB);    // [32768][512] bf16, 32MB
    u16*  vtt   = (u16*)(ws + 64 * MB);    // V^T [512][32768] bf16, 32MB
    u16*  qbuf  = (u16*)(ws + 96 * MB);    // [16384][512] bf16, 16MB (compact patch)
    u16*  obuf  = (u16*)(ws + 112 * MB);   // 16MB
    u16*  xbuf16 = (u16*)(ws + 128 * MB);  // x residual [16384][512] bf16, 16MB
    u16*  h2buf = (u16*)(ws + 160 * MB);   // 16MB
    u16*  tbuf  = (u16*)(ws + 0);          // [16384][2048] bf16, 64MB (reuse h+k, dead)
    u16*  xfbuf = (u16*)(ws + 64 * MB);    // [16384][512] bf16, 16MB (reuse vtt, dead)
    u16* wqkvT = (u16*)(ws + 176 * MB);    // [1536][512] bf16, 1.5MB (q rows pre-scaled)
    u16* woT  = (u16*)(ws + 177 * MB + 512 * 1024);
    u16* w1T  = (u16*)(ws + 178 * MB);     // [2048][512], 2MB
    u16* w2T  = (u16*)(ws + 180 * MB);     // [512][2048], 2MB
    int* sel = (int*)(ws + 182 * MB);      // 64KB
    unsigned char* validk = (unsigned char*)(ws + 182 * MB + 64 * 1024); // 32KB
    int* flagp = (int*)(ws + 182 * MB + 128 * 1024);
    float* bqkv = (float*)(ws + 182 * MB + 132 * 1024);  // [1536] f32
    int* wcnt = (int*)(ws + 182 * MB + 140 * 1024);      // [64] valid-voxel counts

    detect_kernel<<<1, 256, 0, stream>>>((const u32*)patch, flagp);

    wtrans_all_kernel<<<3072, dim3(32, 8), 0, stream>>>(wq, wk, wv, wo, w1, w2,
        wqkvT, woT, w1T, w2T, flagp);
    prep_bias_kernel<<<6, 256, 0, stream>>>(bq, bk, bv, flagp, bqkv);

    voxsel_kernel<<<NWIN, 64, 0, stream>>>(vpy, vpx, sel, wcnt);
    ln1_kernel<<<NROW / 4, 256, 0, stream>>>(patch, vox, ln1g, ln1b, sel, flagp, hbuf, validk);

    // fused QKV gemm: one tile/block, XCD-local remap + empty voxel-tile skip
    gemm_kernel<<<dim3(12, NROW / 128), 256, 0, stream>>>(hbuf, wqkvT, bqkv,
        qbuf, kbuf, vtt, nullptr, flagp, wcnt, NROW, 1536, 512, GF_QKV, 512);

    attn_kernel<<<dim3(HEADS, NWIN), 256, 0, stream>>>(qbuf, kbuf, vtt, validk, wcnt, obuf);

    // x = tokens(patch gather) + o @ wo + bo   (bf16, coalesced staged store)
    gemm_kernel<<<dim3(4, NPATCH / 128), 256, 0, stream>>>(obuf, woT, bo,
        xbuf16, nullptr, nullptr, patch, flagp, wcnt, NPATCH, 512, 512, GF_RES_PATCH, 512);

    ln2_kernel<<<NPATCH / 4, 256, 0, stream>>>(xbuf16, ln2g, ln2b, flagp, h2buf);

    gemm_kernel<<<dim3(16, NPATCH / 128), 256, 0, stream>>>(h2buf, w1T, b1,
        tbuf, nullptr, nullptr, nullptr, flagp, wcnt, NPATCH, 2048, 512, GF_GELU, 2048);
    gemm_kernel<<<dim3(4, NPATCH / 128), 256, 0, stream>>>(tbuf, w2T, b2,
        xfbuf, nullptr, nullptr, xbuf16, flagp, wcnt, NPATCH, 512, 2048, GF_RES_BF16, 512);

    gather_kernel<<<(4096 * 128) / 256, 256, 0, stream>>>(xfbuf, d_out, flagp);
}

// Round 10
// 427.060 us; speedup vs baseline: 1.6556x; 1.0352x over previous
//
#include <hip/hip_runtime.h>
#include <math.h>

using u16 = unsigned short;
using u32 = unsigned int;
using u64 = unsigned long long;
using bf16x8 = __attribute__((ext_vector_type(8))) short;
using f32x4  = __attribute__((ext_vector_type(4))) float;

#define C_DIM   512
#define HEADS   8
#define HDIM    64
#define P_DIM   64
#define A_TOK   256
#define VCAP    256
#define S_TOK   512
#define NWIN    64
#define NROW    32768      // NWIN * S_TOK
#define NPATCH  16384      // NWIN * A_TOK
#define MLP_DIM 2048
#define NV_TOT  2048
#define LOG2E   1.44269504088896f

__device__ __forceinline__ float bf2f(u16 b) { return __uint_as_float(((u32)b) << 16); }
__device__ __forceinline__ u16 f2bf(float f) {
    u32 u = __float_as_uint(f);
    return (u16)((u + 0x7fffu + ((u >> 16) & 1u)) >> 16);   // RNE
}
__device__ __forceinline__ float4 bf4f(ushort4 v) {
    return make_float4(bf2f(v.x), bf2f(v.y), bf2f(v.z), bf2f(v.w));
}
// dtype-agnostic loads from RAW inputs: isbf=1 -> bf16, else f32
__device__ __forceinline__ float ldf(const void* p, size_t e, int isbf) {
    return isbf ? bf2f(((const u16*)p)[e]) : ((const float*)p)[e];
}
__device__ __forceinline__ float4 ld4(const void* p, size_t e, int isbf) {  // e % 4 == 0
    if (isbf) return bf4f(*(const ushort4*)((const u16*)p + e));
    return *(const float4*)((const float*)p + e);
}
// async global->LDS, 16B per lane; lds dest must be wave-uniform-base + lane*16
__device__ __forceinline__ void gload16(const u16* g, u16* l) {
    __builtin_amdgcn_global_load_lds(
        (const __attribute__((address_space(1))) u32*)g,
        (__attribute__((address_space(3))) u32*)l, 16, 0, 0);
}
// tanh-form GELU via sigmoid: x*sigmoid(1.5957691x + 0.0713548x^3); |err| <= ~3e-4
__device__ __forceinline__ float fast_gelu(float x) {
    float x2 = x * x;
    float z = x * (-1.5957691216f - 0.07135481283f * x2);
    return x / (1.f + __expf(z));
}
// per-block dtype self-detection: vote on low-16-bits-as-bf16 plausibility (L2-resident scan)
__device__ __forceinline__ int self_detect(const u32* patch, int tid, int* sm)
{
    int cnt = 0;
    for (int i = tid; i < 4096; i += 256) {
        u32 w = patch[i];
        float a = fabsf(__uint_as_float((w & 0xffffu) << 16));
        if (a > 1e-8f && a < 1e4f) cnt++;
    }
    sm[tid] = cnt;
    __syncthreads();
    for (int o = 128; o; o >>= 1) { if (tid < o) sm[tid] += sm[tid + o]; __syncthreads(); }
    int r = (sm[0] > 2458) ? 1 : 0;
    __syncthreads();
    return r;
}

// ------------- merged setup: weight transposes + voxel selection + bias prep + flag -------------
// blocks 0..3071: wtrans; 3072..3135: voxsel; 3136..3141: bias prep. Every block self-detects.
__global__ __launch_bounds__(256) void setup_kernel(
    const void* __restrict__ wq, const void* __restrict__ wk,
    const void* __restrict__ wv, const void* __restrict__ wo,
    const void* __restrict__ w1, const void* __restrict__ w2,
    const void* __restrict__ bq, const void* __restrict__ bk, const void* __restrict__ bv,
    const void* __restrict__ patch,
    const int* __restrict__ vy, const int* __restrict__ vx,
    u16* __restrict__ wqkvT, u16* __restrict__ woT,
    u16* __restrict__ w1T, u16* __restrict__ w2T,
    float* __restrict__ bqkv, int* __restrict__ sel, int* __restrict__ wcnt,
    int* __restrict__ flagp)
{
    __shared__ int sm[256];
    __shared__ u16 tile[32][33];
    int tx = threadIdx.x, ty = threadIdx.y;          // block (32,8)
    int tid = ty * 32 + tx;
    int isbf = self_detect((const u32*)patch, tid, sm);
    int bid = blockIdx.x;
    if (bid == 0 && tid == 0) *flagp = isbf;

    if (bid < 3072) {
        int id = bid;
        const void* in; u16* out; int K, N; float sc = 1.f;
        if (id < 256)       { in = wq; out = wqkvT;              K = 512;  N = 512;  sc = 0.125f * LOG2E; }
        else if (id < 512)  { id -= 256;  in = wk; out = wqkvT + 512 * 512;  K = 512;  N = 512; }
        else if (id < 768)  { id -= 512;  in = wv; out = wqkvT + 1024 * 512; K = 512;  N = 512; }
        else if (id < 1024) { id -= 768;  in = wo; out = woT;    K = 512;  N = 512; }
        else if (id < 2048) { id -= 1024; in = w1; out = w1T;    K = 512;  N = 2048; }
        else                { id -= 2048; in = w2; out = w2T;    K = 2048; N = 512; }
        int ntx = N >> 5;
        int n0 = (id % ntx) * 32, k0 = (id / ntx) * 32;
        #pragma unroll
        for (int i = 0; i < 4; i++)
            tile[ty + i * 8][tx] = f2bf(sc * ldf(in, (size_t)(k0 + ty + i * 8) * N + (n0 + tx), isbf));
        __syncthreads();
        #pragma unroll
        for (int i = 0; i < 4; i++)
            out[(size_t)(n0 + ty + i * 8) * K + (k0 + tx)] = tile[tx][ty + i * 8];
    } else if (bid < 3136) {
        if (tid < 64) {                               // first wave only (64-lane ballot)
            int n = bid - 3072, lane = tid;
            int y0 = (n >> 3) << 3, x0 = (n & 7) << 3;
            int count = 0;
            for (int base = 0; base < NV_TOT; base += 64) {
                int v = base + lane;
                int yy = vy[v], xx = vx[v];
                bool m = (yy >= y0) && (yy < y0 + 16) && (xx >= x0) && (xx < x0 + 16);
                u64 mask = __ballot(m);
                int pos = count + __popcll(mask & ((1ull << lane) - 1ull));
                if (m && pos < VCAP) sel[n * VCAP + pos] = v;
                count += __popcll(mask);
            }
            for (int j = lane; j < VCAP; j += 64)
                if (j >= count) sel[n * VCAP + j] = -1;
            if (lane == 0) wcnt[n] = count < VCAP ? count : VCAP;
        }
    } else {
        int t = (bid - 3136) * 256 + tid;             // q bias pre-scaled incl. log2(e)
        if (t < 512)       bqkv[t] = 0.125f * LOG2E * ldf(bq, t, isbf);
        else if (t < 1024) bqkv[t] = ldf(bk, t - 512, isbf);
        else if (t < 1536) bqkv[t] = ldf(bv, t - 1024, isbf);
    }
}

// ---------------- gather tokens + LN1 -> h (bf16), validity flags ----------------
__global__ __launch_bounds__(256) void ln1_kernel(
    const void* __restrict__ patch, const void* __restrict__ vox,
    const void* __restrict__ g, const void* __restrict__ b,
    const int* __restrict__ sel, const int* __restrict__ flagp,
    u16* __restrict__ h, unsigned char* __restrict__ validk)
{
    int isbf = *flagp;
    int r = blockIdx.x * 4 + (threadIdx.x >> 6);    // one wave per row
    int lane = threadIdx.x & 63;
    int n = r >> 9, s = r & 511;
    const void* tok = nullptr;
    size_t base = 0;
    bool valid;
    if (s < A_TOK) {
        int wy = s >> 4, wx = s & 15;
        int iy = ((n >> 3) << 3) + wy, ix = ((n & 7) << 3) + wx;
        valid = (iy < P_DIM) && (ix < P_DIM);
        tok = patch; base = (size_t)(iy * P_DIM + ix) * C_DIM;
    } else {
        int idx = sel[n * VCAP + (s - A_TOK)];
        valid = (idx >= 0);
        tok = vox; base = valid ? (size_t)idx * C_DIM : 0;
    }
    float4 xa = make_float4(0.f, 0.f, 0.f, 0.f), xb = xa;
    if (valid) {
        xa = ld4(tok, base + lane * 4, isbf);
        xb = ld4(tok, base + 256 + lane * 4, isbf);
    }
    float sum = xa.x + xa.y + xa.z + xa.w + xb.x + xb.y + xb.z + xb.w;
    float sq  = xa.x * xa.x + xa.y * xa.y + xa.z * xa.z + xa.w * xa.w
              + xb.x * xb.x + xb.y * xb.y + xb.z * xb.z + xb.w * xb.w;
    #pragma unroll
    for (int off = 32; off; off >>= 1) {
        sum += __shfl_xor(sum, off, 64);
        sq  += __shfl_xor(sq,  off, 64);
    }
    float mean = sum * (1.f / C_DIM);
    float var  = fmaxf(sq * (1.f / C_DIM) - mean * mean, 0.f);
    float rstd = rsqrtf(var + 1e-5f);
    float4 ga = ld4(g, lane * 4, isbf);
    float4 gb = ld4(g, 256 + lane * 4, isbf);
    float4 ba = ld4(b, lane * 4, isbf);
    float4 bb = ld4(b, 256 + lane * 4, isbf);
    ushort4 oa, ob;
    oa.x = f2bf((xa.x - mean) * rstd * ga.x + ba.x);
    oa.y = f2bf((xa.y - mean) * rstd * ga.y + ba.y);
    oa.z = f2bf((xa.z - mean) * rstd * ga.z + ba.z);
    oa.w = f2bf((xa.w - mean) * rstd * ga.w + ba.w);
    ob.x = f2bf((xb.x - mean) * rstd * gb.x + bb.x);
    ob.y = f2bf((xb.y - mean) * rstd * gb.y + bb.y);
    ob.z = f2bf((xb.z - mean) * rstd * gb.z + bb.z);
    ob.w = f2bf((xb.w - mean) * rstd * gb.w + bb.w);
    ((ushort4*)(h + (size_t)r * C_DIM))[lane]      = oa;
    ((ushort4*)(h + (size_t)r * C_DIM))[lane + 64] = ob;
    if (lane == 0) validk[r] = valid ? 1 : 0;
}

// ---------------- LN2 over bf16 rows -> bf16 ----------------
__global__ __launch_bounds__(256) void ln2_kernel(
    const u16* __restrict__ x,
    const void* __restrict__ g, const void* __restrict__ b,
    const int* __restrict__ flagp,
    u16* __restrict__ h2)
{
    int isbf = *flagp;
    int r = blockIdx.x * 4 + (threadIdx.x >> 6);
    int lane = threadIdx.x & 63;
    const u16* src = x + (size_t)r * C_DIM;
    float4 xa = bf4f(((const ushort4*)src)[lane]);
    float4 xb = bf4f(((const ushort4*)src)[lane + 64]);
    float sum = xa.x + xa.y + xa.z + xa.w + xb.x + xb.y + xb.z + xb.w;
    float sq  = xa.x * xa.x + xa.y * xa.y + xa.z * xa.z + xa.w * xa.w
              + xb.x * xb.x + xb.y * xb.y + xb.z * xb.z + xb.w * xb.w;
    #pragma unroll
    for (int off = 32; off; off >>= 1) {
        sum += __shfl_xor(sum, off, 64);
        sq  += __shfl_xor(sq,  off, 64);
    }
    float mean = sum * (1.f / C_DIM);
    float var  = fmaxf(sq * (1.f / C_DIM) - mean * mean, 0.f);
    float rstd = rsqrtf(var + 1e-5f);
    float4 ga = ld4(g, lane * 4, isbf);
    float4 gb = ld4(g, 256 + lane * 4, isbf);
    float4 ba = ld4(b, lane * 4, isbf);
    float4 bb = ld4(b, 256 + lane * 4, isbf);
    ushort4 oa, ob;
    oa.x = f2bf((xa.x - mean) * rstd * ga.x + ba.x);
    oa.y = f2bf((xa.y - mean) * rstd * ga.y + ba.y);
    oa.z = f2bf((xa.z - mean) * rstd * ga.z + ba.z);
    oa.w = f2bf((xa.w - mean) * rstd * ga.w + ba.w);
    ob.x = f2bf((xb.x - mean) * rstd * gb.x + bb.x);
    ob.y = f2bf((xb.y - mean) * rstd * gb.y + bb.y);
    ob.z = f2bf((xb.z - mean) * rstd * gb.z + bb.z);
    ob.w = f2bf((xb.w - mean) * rstd * gb.w + bb.w);
    ((ushort4*)(h2 + (size_t)r * C_DIM))[lane]      = oa;
    ((ushort4*)(h2 + (size_t)r * C_DIM))[lane + 64] = ob;
}

// ---------------- generic bf16 MFMA GEMM: C = op(A @ B^T + bias), one tile/block ----------------
// XCD-local block remap for ALL dispatches (gridDim.y % 8 == 0): all gridDim.x n-tiles of an
// m-tile run adjacently on one XCD (xcd = linear_id % 8 heuristic) -> A-tile hits one L2.
#define GF_GELU      2
#define GF_RES_BF16  8    // += res (bf16, [M][N])
#define GF_RES_PATCH 16   // += gathered patch token (raw dtype), valid positions only
#define GF_QKV       32   // N=1536: cols 0-511 q (compact, patch rows), 512-1023 k, 1024-1535 v^T
#define GF_PATCHM    64   // m rows are compact patch rows: skip fully-OOB edge tiles

__global__ __launch_bounds__(256) void gemm_kernel(
    const u16* __restrict__ A, const u16* __restrict__ BT,
    const void* __restrict__ bias,
    void* __restrict__ Cout, void* __restrict__ Cout2, void* __restrict__ Cout3,
    const void* __restrict__ resv,
    const int* __restrict__ flagp, const int* __restrict__ wcnt,
    int M, int N, int K, int flags, int ldc)
{
    __shared__ u16 smem[2 * 128 * 64];   // As = smem, Bs = smem+8192 (u16); epilogue stage reuse
    int tid = threadIdx.x;
    int nt, mt;
    int gx = gridDim.x, gy = gridDim.y;
    if ((gy & 7) == 0) {
        // XCD-local remap: linear id L (x fastest), xcd = L % 8 (round-robin heuristic).
        int L = blockIdx.x + gx * blockIdx.y;
        int c = L & 7, s = L >> 3;
        mt = c * (gy >> 3) + s / gx;
        nt = s % gx;
    } else { nt = blockIdx.x; mt = blockIdx.y; }
    int m0 = mt << 7, n0 = nt << 7;
    int region = (flags & GF_QKV) ? (nt >> 2) : 0;   // 0:q 1:k 2:v^T
    if (flags & GF_QKV) {
        int lo = m0 & 511;
        if (region == 0) {
            if (lo >= 256) return;                   // voxel rows need no Q
            // edge skip: window grid-row 7, s in [128,256) -> all iy >= 64 (never consumed)
            if (((m0 >> 9) >> 3) == 7 && ((m0 >> 7) & 3) == 1) return;
        }
        // empty voxel-slot tiles need no K/V (poison stays; attention masks/skips them)
        if (region >= 1 && lo >= 256 && wcnt[m0 >> 9] <= lo - 256) return;
    }
    if (flags & GF_PATCHM) {
        int n = mt >> 1;                              // window index (128 rows = half window)
        if ((n >> 3) == 7 && (mt & 1) == 1) return;   // fully-OOB edge tile, rows never consumed
    }
    int isbf = *flagp;
    int w = tid >> 6, lane = tid & 63;
    int wr = (w >> 1) * 64, wc = (w & 1) * 64;
    int l16 = lane & 15, quad = lane >> 4;
    u16* As = smem;
    u16* Bs = smem + 8192;
    bool vtb = (flags & GF_QKV) && (region == 2);   // transposed-output block

    f32x4 acc[4][4];
    #pragma unroll
    for (int i = 0; i < 4; i++)
        #pragma unroll
        for (int j = 0; j < 4; j++) { acc[i][j][0] = 0.f; acc[i][j][1] = 0.f; acc[i][j][2] = 0.f; acc[i][j][3] = 0.f; }

    int swz = (l16 & 7);                   // frag-read chunk swizzle key
    const u16* Xs = vtb ? Bs : As;         // first operand rows -> D rows
    const u16* Ys = vtb ? As : Bs;
    for (int k0 = 0; k0 < K; k0 += 64) {
        #pragma unroll
        for (int it = 0; it < 4; it++) {
            int c = (it * 4 + w) * 64 + lane;   // 0..1023 chunk slots
            int row = c >> 3, phys = c & 7;
            int kc = phys ^ (row & 7);          // XOR swizzle: break 128B-stride bank aliasing
            gload16(A  + (size_t)(m0 + row) * K + k0 + kc * 8, As + (size_t)c * 8);
            gload16(BT + (size_t)(n0 + row) * K + k0 + kc * 8, Bs + (size_t)c * 8);
        }
        __syncthreads();
        #pragma unroll
        for (int ks = 0; ks < 2; ks++) {
            bf16x8 a[4], b[4];
            #pragma unroll
            for (int i = 0; i < 4; i++) {
                int chunk = (ks * 4 + quad) ^ swz;
                a[i] = *(const bf16x8*)&Xs[(wr + i * 16 + l16) * 64 + chunk * 8];
            }
            #pragma unroll
            for (int j = 0; j < 4; j++) {
                int chunk = (ks * 4 + quad) ^ swz;
                b[j] = *(const bf16x8*)&Ys[(wc + j * 16 + l16) * 64 + chunk * 8];
            }
            #pragma unroll
            for (int i = 0; i < 4; i++)
                #pragma unroll
                for (int j = 0; j < 4; j++)
                    acc[i][j] = __builtin_amdgcn_mfma_f32_16x16x32_bf16(a[i], b[j], acc[i][j], 0, 0, 0);
        }
        __syncthreads();
    }

    // ---------- epilogue (bf16, LDS-staged, coalesced 128B rows) ----------
    u16* st = smem + w * 4096;          // per-wave 64x64 bf16 stage (reuses tile LDS)
    #pragma unroll
    for (int i = 0; i < 4; i++) {
        #pragma unroll
        for (int j = 0; j < 4; j++) {
            int gcol = n0 + wc + j * 16 + l16;
            float bc = 0.f;
            if (flags & GF_QKV) { if (!vtb) bc = ((const float*)bias)[gcol]; }
            else if (bias) bc = ldf(bias, gcol, isbf);
            #pragma unroll
            for (int r2 = 0; r2 < 4; r2++) {
                int lrow = wr + i * 16 + quad * 4 + r2;
                int grow = m0 + lrow;
                if (vtb) bc = ((const float*)bias)[n0 + lrow];   // channel-indexed bias
                float v = acc[i][j][r2] + bc;
                if (flags & GF_GELU) v = fast_gelu(v);
                if (flags & GF_RES_BF16) v += bf2f(((const u16*)resv)[(size_t)grow * N + gcol]);
                if (flags & GF_RES_PATCH) {
                    int nn = grow >> 8, s = grow & 255;
                    int iy = ((nn >> 3) << 3) + (s >> 4);
                    int ix = ((nn & 7) << 3) + (s & 15);
                    if (iy < P_DIM && ix < P_DIM)
                        v += ldf(resv, (size_t)(iy * P_DIM + ix) * C_DIM + gcol, isbf);
                }
                st[(i * 16 + quad * 4 + r2) * 64 + j * 16 + l16] = f2bf(v);
            }
        }
    }
    asm volatile("" ::: "memory");   // same-wave LDS: block reorder, no barrier needed
    u16* cdst; int cst;
    if (flags & GF_QKV) {
        if (region == 0) {          // q: compact patch rows, pre-scaled
            cst = 512;
            cdst = (u16*)Cout  + (size_t)(((m0 >> 9) << 8) + (m0 & 255) + wr) * 512 + (n0 + wc);
        } else if (region == 1) {   // k
            cst = 512;
            cdst = (u16*)Cout2 + (size_t)(m0 + wr) * 512 + (n0 - 512 + wc);
        } else {                    // v^T: rows = channels, cols = tokens
            cst = NROW;
            cdst = (u16*)Cout3 + (size_t)(n0 - 1024 + wr) * NROW + (m0 + wc);
        }
    } else {
        cst = ldc;
        cdst = (u16*)Cout + (size_t)(m0 + wr) * ldc + (n0 + wc);
    }
    #pragma unroll
    for (int rr = 0; rr < 8; rr++) {
        int row = rr * 8 + (lane >> 3);
        uint4 val = *(const uint4*)&st[row * 64 + (lane & 7) * 8];
        *(uint4*)(cdst + (size_t)row * cst + (lane & 7) * 8) = val;   // 128B/row coalesced
    }
}

// ---------------- flash attention per (window, head); patch queries only ----------------
// scores arrive in log2 domain (log2e folded into q scale); P = exp2(s) = e^(s/log2e)
__global__ __launch_bounds__(256) void attn_kernel(
    const u16* __restrict__ q, const u16* __restrict__ k, const u16* __restrict__ vtg,
    const unsigned char* __restrict__ validk, const int* __restrict__ wcnt,
    u16* __restrict__ o)
{
    __shared__ u16 sK[64 * 64];          // [key][d], DMA-staged, swizzled chunks
    __shared__ u16 sV[64 * 64];          // [d][key], DMA-staged from V^T, swizzled chunks
    __shared__ u16 sP[4 * 64 * 64];      // per-wave P tile, chunk-swizzled (48KB total LDS)
    int h = blockIdx.x, n = blockIdx.y;
    int tid = threadIdx.x;
    int w = tid >> 6, lane = tid & 63;
    int l16 = lane & 15, quad = lane >> 4;
    int swz = (l16 & 7);
    int cnt = wcnt[n];                   // valid voxel slots in this window

    bf16x8 qf[4][2];
    #pragma unroll
    for (int i = 0; i < 4; i++)
        #pragma unroll
        for (int ks = 0; ks < 2; ks++) {
            int row = n * A_TOK + w * 64 + i * 16 + l16;       // compact q
            int col = h * HDIM + ks * 32 + quad * 8;
            qf[i][ks] = *(const bf16x8*)(q + (size_t)row * C_DIM + col);
        }

    f32x4 oacc[4][4];
    float lsum[4][4];
    #pragma unroll
    for (int i = 0; i < 4; i++)
        #pragma unroll
        for (int j = 0; j < 4; j++) {
            oacc[i][j][0] = 0.f; oacc[i][j][1] = 0.f; oacc[i][j][2] = 0.f; oacc[i][j][3] = 0.f;
            lsum[i][j] = 0.f;
        }

    for (int ktile = 0; ktile < 8; ktile++) {
        // voxel key-tiles past the valid count are entirely masked -> skip (block-uniform, monotone)
        if (ktile >= 4 && cnt <= (ktile - 4) * 64) break;
        __syncthreads();                       // prior tile's readers done before overwrite
        #pragma unroll
        for (int it = 0; it < 2; it++) {
            int c = it * 256 + w * 64 + lane;  // 0..511 chunk slots
            int row = c >> 3, phys = c & 7;
            int kc = phys ^ (row & 7);
            int grow = n * S_TOK + ktile * 64 + row;
            gload16(k + (size_t)grow * C_DIM + h * HDIM + kc * 8, sK + (size_t)c * 8);
            gload16(vtg + (size_t)(h * HDIM + row) * (size_t)NROW + n * S_TOK + ktile * 64 + kc * 8,
                    sV + (size_t)c * 8);
        }
        __syncthreads();

        f32x4 sacc[4][4];
        #pragma unroll
        for (int i = 0; i < 4; i++)
            #pragma unroll
            for (int j = 0; j < 4; j++) { sacc[i][j][0] = 0.f; sacc[i][j][1] = 0.f; sacc[i][j][2] = 0.f; sacc[i][j][3] = 0.f; }
        #pragma unroll
        for (int ks = 0; ks < 2; ks++) {
            int chunk = (ks * 4 + quad) ^ swz;
            bf16x8 bfr[4];
            #pragma unroll
            for (int j = 0; j < 4; j++) bfr[j] = *(const bf16x8*)&sK[(j * 16 + l16) * 64 + chunk * 8];
            #pragma unroll
            for (int i = 0; i < 4; i++)
                #pragma unroll
                for (int j = 0; j < 4; j++)
                    sacc[i][j] = __builtin_amdgcn_mfma_f32_16x16x32_bf16(qf[i][ks], bfr[j], sacc[i][j], 0, 0, 0);
        }

        bool kvalid[4];
        #pragma unroll
        for (int j = 0; j < 4; j++)
            kvalid[j] = validk[n * S_TOK + ktile * 64 + j * 16 + l16] != 0;

        #pragma unroll
        for (int i = 0; i < 4; i++)
            #pragma unroll
            for (int r2 = 0; r2 < 4; r2++) {
                int prow = i * 16 + quad * 4 + r2;
                #pragma unroll
                for (int j = 0; j < 4; j++) {
                    float p = kvalid[j] ? exp2f(sacc[i][j][r2]) : 0.f;
                    lsum[i][r2] += p;
                    int col = j * 16 + l16;
                    int chunk = (col >> 3) ^ (prow & 7);
                    sP[(w * 64 + prow) * 64 + chunk * 8 + (col & 7)] = f2bf(p);
                }
            }
        asm volatile("" ::: "memory");   // per-wave LDS: forbid read-before-write reorder
        #pragma unroll
        for (int ks = 0; ks < 2; ks++) {
            int chunk = (ks * 4 + quad) ^ swz;
            bf16x8 pa[4], vb[4];
            #pragma unroll
            for (int i = 0; i < 4; i++)   pa[i]  = *(const bf16x8*)&sP[(w * 64 + i * 16 + l16) * 64 + chunk * 8];
            #pragma unroll
            for (int jd = 0; jd < 4; jd++) vb[jd] = *(const bf16x8*)&sV[(jd * 16 + l16) * 64 + chunk * 8];
            #pragma unroll
            for (int i = 0; i < 4; i++)
                #pragma unroll
                for (int jd = 0; jd < 4; jd++)
                    oacc[i][jd] = __builtin_amdgcn_mfma_f32_16x16x32_bf16(pa[i], vb[jd], oacc[i][jd], 0, 0, 0);
        }
    }

    // normalize, stage O per-wave in LDS, coalesced 128B stores
    asm volatile("" ::: "memory");
    __syncthreads();                     // all waves done with sP/sV before O staging reuse
    u16* ost = sP + w * 4096;            // flat 64x64 region, stride 64 (sP data dead)
    #pragma unroll
    for (int i = 0; i < 4; i++) {
        #pragma unroll
        for (int r2 = 0; r2 < 4; r2++) {
            float l = lsum[i][r2];
            #pragma unroll
            for (int off = 8; off; off >>= 1)
                l += __shfl_xor(l, off, 64);
            float inv = (l > 0.f) ? 1.f / l : 0.f;
            #pragma unroll
            for (int jd = 0; jd < 4; jd++)
                ost[(i * 16 + quad * 4 + r2) * 64 + jd * 16 + l16] = f2bf(oacc[i][jd][r2] * inv);
        }
    }
    asm volatile("" ::: "memory");
    u16* obase = o + (size_t)(n * A_TOK + w * 64) * C_DIM + h * HDIM;
    #pragma unroll
    for (int rr = 0; rr < 8; rr++) {
        int row = rr * 8 + (lane >> 3);
        uint4 val = *(const uint4*)&ost[row * 64 + (lane & 7) * 8];
        *(uint4*)(obase + (size_t)row * C_DIM + (lane & 7) * 8) = val;
    }
}

// ---------------- final gather-average (bf16 input) ----------------
__global__ __launch_bounds__(256) void gather_kernel(const u16* __restrict__ xf,
                                                     void* __restrict__ out,
                                                     const int* __restrict__ flagp)
{
    int isbf = *flagp;
    int gid = blockIdx.x * 256 + threadIdx.x;    // pixel*128 + 4-elem chunk
    int p = gid >> 7, cv = gid & 127;
    int py = p >> 6, px = p & 63;
    float4 acc = make_float4(0.f, 0.f, 0.f, 0.f);
    int cnt = 0;
    #pragma unroll
    for (int dy = 0; dy < 2; dy++) {
        int y0 = ((py >> 3) - dy) << 3;
        if (y0 < 0) continue;
        #pragma unroll
        for (int dx = 0; dx < 2; dx++) {
            int x0 = ((px >> 3) - dx) << 3;
            if (x0 < 0) continue;
            int n = ((y0 >> 3) << 3) + (x0 >> 3);
            int s = (py - y0) * 16 + (px - x0);
            float4 t = bf4f(((const ushort4*)(xf + (size_t)(n * A_TOK + s) * C_DIM))[cv]);
            acc.x += t.x; acc.y += t.y; acc.z += t.z; acc.w += t.w;
            cnt++;
        }
    }
    float inv = 1.f / (float)cnt;
    acc.x *= inv; acc.y *= inv; acc.z *= inv; acc.w *= inv;
    if (isbf) {
        ushort4 o;
        o.x = f2bf(acc.x); o.y = f2bf(acc.y); o.z = f2bf(acc.z); o.w = f2bf(acc.w);
        ((ushort4*)out)[gid] = o;
    } else {
        ((float4*)out)[gid] = acc;
    }
}

extern "C" void kernel_launch(void* const* d_in, const int* in_sizes, int n_in,
                              void* d_out, int out_size, void* d_ws, size_t ws_size,
                              hipStream_t stream)
{
    const void* patch = d_in[0];
    const void* vox   = d_in[1];
    const void* ln1g  = d_in[2];
    const void* ln1b  = d_in[3];
    const void* wq = d_in[4];  const void* bq = d_in[5];
    const void* wk = d_in[6];  const void* bk = d_in[7];
    const void* wv = d_in[8];  const void* bv = d_in[9];
    const void* wo = d_in[10]; const void* bo = d_in[11];
    const void* ln2g = d_in[12];
    const void* ln2b = d_in[13];
    const void* w1 = d_in[14]; const void* b1 = d_in[15];
    const void* w2 = d_in[16]; const void* b2 = d_in[17];
    const int* vpy = (const int*)d_in[18];
    const int* vpx = (const int*)d_in[19];

    const size_t MB = 1ull << 20;
    char* ws = (char*)d_ws;
    if (ws_size < 183 * MB) return;   // insufficient workspace -> visible failure

    u16*  hbuf  = (u16*)(ws + 0);          // [32768][512] bf16, 32MB
    u16*  kbuf  = (u16*)(ws + 32 * MB);    // [32768][512] bf16, 32MB
    u16*  vtt   = (u16*)(ws + 64 * MB);    // V^T [512][32768] bf16, 32MB
    u16*  qbuf  = (u16*)(ws + 96 * MB);    // [16384][512] bf16, 16MB (compact patch)
    u16*  obuf  = (u16*)(ws + 112 * MB);   // 16MB
    u16*  xbuf16 = (u16*)(ws + 128 * MB);  // x residual [16384][512] bf16, 16MB
    u16*  h2buf = (u16*)(ws + 160 * MB);   // 16MB
    u16*  tbuf  = (u16*)(ws + 0);          // [16384][2048] bf16, 64MB (reuse h+k, dead)
    u16*  xfbuf = (u16*)(ws + 64 * MB);    // [16384][512] bf16, 16MB (reuse vtt, dead)
    u16* wqkvT = (u16*)(ws + 176 * MB);    // [1536][512] bf16, 1.5MB (q rows pre-scaled)
    u16* woT  = (u16*)(ws + 177 * MB + 512 * 1024);
    u16* w1T  = (u16*)(ws + 178 * MB);     // [2048][512], 2MB
    u16* w2T  = (u16*)(ws + 180 * MB);     // [512][2048], 2MB
    int* sel = (int*)(ws + 182 * MB);      // 64KB
    unsigned char* validk = (unsigned char*)(ws + 182 * MB + 64 * 1024); // 32KB
    int* flagp = (int*)(ws + 182 * MB + 128 * 1024);
    float* bqkv = (float*)(ws + 182 * MB + 132 * 1024);  // [1536] f32
    int* wcnt = (int*)(ws + 182 * MB + 140 * 1024);      // [64] valid-voxel counts

    // merged setup: wtrans (3072) + voxsel (64) + bias prep (6); each block self-detects dtype
    setup_kernel<<<3142, dim3(32, 8), 0, stream>>>(wq, wk, wv, wo, w1, w2, bq, bk, bv,
        patch, vpy, vpx, wqkvT, woT, w1T, w2T, bqkv, sel, wcnt, flagp);

    ln1_kernel<<<NROW / 4, 256, 0, stream>>>(patch, vox, ln1g, ln1b, sel, flagp, hbuf, validk);

    // fused QKV gemm: one tile/block, XCD-local remap + voxel/edge tile skip
    gemm_kernel<<<dim3(12, NROW / 128), 256, 0, stream>>>(hbuf, wqkvT, bqkv,
        qbuf, kbuf, vtt, nullptr, flagp, wcnt, NROW, 1536, 512, GF_QKV, 512);

    attn_kernel<<<dim3(HEADS, NWIN), 256, 0, stream>>>(qbuf, kbuf, vtt, validk, wcnt, obuf);

    // x = tokens(patch gather) + o @ wo + bo   (bf16, coalesced staged store)
    gemm_kernel<<<dim3(4, NPATCH / 128), 256, 0, stream>>>(obuf, woT, bo,
        xbuf16, nullptr, nullptr, patch, flagp, wcnt, NPATCH, 512, 512, GF_RES_PATCH | GF_PATCHM, 512);

    ln2_kernel<<<NPATCH / 4, 256, 0, stream>>>(xbuf16, ln2g, ln2b, flagp, h2buf);

    gemm_kernel<<<dim3(16, NPATCH / 128), 256, 0, stream>>>(h2buf, w1T, b1,
        tbuf, nullptr, nullptr, nullptr, flagp, wcnt, NPATCH, 2048, 512, GF_GELU | GF_PATCHM, 2048);
    gemm_kernel<<<dim3(4, NPATCH / 128), 256, 0, stream>>>(tbuf, w2T, b2,
        xfbuf, nullptr, nullptr, xbuf16, flagp, wcnt, NPATCH, 512, 2048, GF_RES_BF16 | GF_PATCHM, 512);

    gather_kernel<<<(4096 * 128) / 256, 256, 0, stream>>>(xfbuf, d_out, flagp);
}